// Round 4
// baseline (12341.911 us; speedup 1.0000x reference)
//
#include <hip/hip_runtime.h>
#include <hip/hip_bf16.h>

// problem sizes
constexpr int Bz = 2, IMG = 512, Pp = 16, D = 384, E = 768, S = 16, L = 12;
constexpr int G = IMG / Pp;          // 32
constexpr int Np = G * G;            // 1024 patches
constexpr int M = Bz * Np;           // 2048 rows
constexpr int TWO_E = 2 * E;         // 1536

// ---------------- patchify: pixels(f32) -> A matrix (M x 768) f32 ----------------
__global__ void patchify_kernel(const float* __restrict__ px, float* __restrict__ out){
  int idx = blockIdx.x * 256 + threadIdx.x;     // m*768 + k
  if (idx >= M * 768) return;
  int k = idx % 768, m = idx / 768;
  int b = m / Np, n = m % Np;
  int gy = n / G, gx = n % G;
  int c = k / (Pp * Pp), r = k % (Pp * Pp);
  int py = r / Pp, pxi = r % Pp;
  size_t src = ((size_t)(b * 3 + c) * IMG + gy * Pp + py) * IMG + gx * Pp + pxi;
  out[idx] = px[src];
}

// ---------------- layernorm over D=384 (f32 -> f32), one wave per row ----------------
__global__ __launch_bounds__(256)
void layernorm_kernel(const float* __restrict__ x, const float* __restrict__ w,
                      const float* __restrict__ bb, float* __restrict__ outf){
  int wave = threadIdx.x >> 6;
  int lane = threadIdx.x & 63;
  int row = blockIdx.x * 4 + wave;
  const float* xr = x + (size_t)row * D;
  float v[6];
  float s = 0.f, sq = 0.f;
  #pragma unroll
  for (int i = 0; i < 6; i++){ v[i] = xr[lane + 64 * i]; s += v[i]; sq += v[i] * v[i]; }
  #pragma unroll
  for (int off = 32; off; off >>= 1){ s += __shfl_xor(s, off); sq += __shfl_xor(sq, off); }
  float mean = s * (1.f / D);
  float var  = sq * (1.f / D) - mean * mean;
  float inv  = 1.0f / sqrtf(var + 1e-5f);
  #pragma unroll
  for (int i = 0; i < 6; i++){
    int c = lane + 64 * i;
    outf[(size_t)row * D + c] = (v[i] - mean) * inv * w[c] + bb[c];
  }
}

// ---------------- tiled GEMM: C[M,N] = A[M,K](f32) * W[N,K](f32)^T + bias ----------------
// EPI: 0 = bias only, 1 = +pos, 2 = in-place residual add into C,
//      3 = softplus+clip (dt)
template<int BN, int TN, int EPI>
__global__ __launch_bounds__(256)
void gemm_kernel(const float* __restrict__ A, int lda, int K,
                 const float* __restrict__ W, const float* __restrict__ bias,
                 float* __restrict__ C, const float* __restrict__ pos, int ncols){
  __shared__ float As[16][64 + 1];
  __shared__ float Ws[16][BN + 1];
  int tid = threadIdx.x;
  int tx = tid & 15, ty = tid >> 4;
  int m0 = blockIdx.y * 64, n0 = blockIdx.x * BN;
  float acc[4][TN];
  #pragma unroll
  for (int i = 0; i < 4; i++)
    #pragma unroll
    for (int j = 0; j < TN; j++) acc[i][j] = 0.f;

  for (int kt = 0; kt < K; kt += 16){
    { // A tile 64x16, scalar loads: thread -> row r, 4 consecutive k
      int r = tid >> 2, kk = (tid & 3) << 2;
      const float* ap = A + (size_t)(m0 + r) * lda + kt + kk;
      As[kk + 0][r] = ap[0]; As[kk + 1][r] = ap[1];
      As[kk + 2][r] = ap[2]; As[kk + 3][r] = ap[3];
    }
    if (BN == 64 || tid < BN * 4){ // W tile BNx16
      int c = tid >> 2, kk = (tid & 3) << 2;
      const float* wp = W + (size_t)(n0 + c) * K + kt + kk;
      Ws[kk + 0][c] = wp[0]; Ws[kk + 1][c] = wp[1];
      Ws[kk + 2][c] = wp[2]; Ws[kk + 3][c] = wp[3];
    }
    __syncthreads();
    #pragma unroll
    for (int k = 0; k < 16; k++){
      float a[4], w[TN];
      #pragma unroll
      for (int i = 0; i < 4; i++) a[i] = As[k][ty * 4 + i];
      #pragma unroll
      for (int j = 0; j < TN; j++) w[j] = Ws[k][tx * TN + j];
      #pragma unroll
      for (int i = 0; i < 4; i++)
        #pragma unroll
        for (int j = 0; j < TN; j++) acc[i][j] += a[i] * w[j];
    }
    __syncthreads();
  }

  #pragma unroll
  for (int i = 0; i < 4; i++){
    int m = m0 + ty * 4 + i;
    #pragma unroll
    for (int j = 0; j < TN; j++){
      int n = n0 + tx * TN + j;
      float v = acc[i][j] + bias[n];
      if constexpr (EPI == 1) v += pos[(size_t)(m & (Np - 1)) * ncols + n];
      if constexpr (EPI == 2) v += C[(size_t)m * ncols + n];
      if constexpr (EPI == 3){
        v = (v > 15.f) ? v : log1pf(expf(v));
        v = fminf(fmaxf(v, 1e-4f), 1.0f);
      }
      C[(size_t)m * ncols + n] = v;
    }
  }
}

// ---------------- depthwise causal conv (K=4) + SiLU, f32 ----------------
__global__ void conv_silu_kernel(const float* __restrict__ xz, const float* __restrict__ cw,
                                 const float* __restrict__ cb, float* __restrict__ xc){
  int idx = blockIdx.x * 256 + threadIdx.x;     // m*E + e
  if (idx >= M * E) return;
  int e = idx % E, m = idx / E;
  int n = m & (Np - 1);
  float acc = cb[e];
  #pragma unroll
  for (int kk = 0; kk < 4; kk++){
    int j = n - 3 + kk;
    if (j >= 0) acc += cw[e * 4 + kk] * xz[(size_t)(m - 3 + kk) * TWO_E + e];
  }
  float sig = 1.f / (1.f + expf(-acc));
  xc[idx] = acc * sig;
}

// ---------------- selective scan: 16 lanes (one per state s) per (b,e) row ----------------
// y aliases dtb: dt[m,e] read by all 16 lanes (lockstep wave) before lane 0 writes y[m,e].
__global__ __launch_bounds__(256)
void scan_kernel(const float* __restrict__ dtb, const float* __restrict__ xc,
                 const float* __restrict__ xz, const float* __restrict__ xBC,
                 const float* __restrict__ Aptr, const float* __restrict__ Dp,
                 float* __restrict__ y){
  int grp = threadIdx.x >> 4;        // 16 rows per block
  int s   = threadIdx.x & 15;
  int r   = blockIdx.x * 16 + grp;   // 0..B*E-1
  int b = r / E, e = r % E;
  float a   = Aptr[e * S + s];
  float dpe = Dp[e];
  float h = 0.f;
  const int base_m = b * Np;
  for (int n = 0; n < Np; n++){
    int m = base_m + n;
    float dt  = dtb[(size_t)m * E + e];
    float xcv = xc[(size_t)m * E + e];
    float xb  = xBC[m * 32 + s];
    float xcs = xBC[m * 32 + 16 + s];
    float dA  = expf(fmaxf(dt * a, -20.f));   // dt>0, a<0 -> upper clip at 0 automatic
    h = dA * h + xb * xcv;
    float p = h * xcs;
    p += __shfl_xor(p, 8); p += __shfl_xor(p, 4);
    p += __shfl_xor(p, 2); p += __shfl_xor(p, 1);
    if (s == 0){
      float z = xz[(size_t)m * TWO_E + E + e];
      float sig = 1.f / (1.f + expf(-z));
      y[(size_t)m * E + e] = (p + dpe * xcv) * (z * sig);
    }
  }
}

extern "C" void kernel_launch(void* const* d_in, const int* in_sizes, int n_in,
                              void* d_out, int out_size, void* d_ws, size_t ws_size,
                              hipStream_t stream){
  const float* px      = (const float*)d_in[0];
  const float* patch_w = (const float*)d_in[1];
  const float* patch_b = (const float*)d_in[2];
  const float* pos     = (const float*)d_in[3];
  const float* norm_w  = (const float*)d_in[4];
  const float* norm_b  = (const float*)d_in[5];
  const float* in_w    = (const float*)d_in[6];
  const float* in_b    = (const float*)d_in[7];
  const float* conv_w  = (const float*)d_in[8];
  const float* conv_b  = (const float*)d_in[9];
  const float* xp_w    = (const float*)d_in[10];
  const float* xp_b    = (const float*)d_in[11];
  const float* dt_w    = (const float*)d_in[12];
  const float* dt_b    = (const float*)d_in[13];
  const float* Aab     = (const float*)d_in[14];
  const float* Dp      = (const float*)d_in[15];
  const float* out_w   = (const float*)d_in[16];
  const float* out_b   = (const float*)d_in[17];
  const float* fnorm_w = (const float*)d_in[18];
  const float* fnorm_b = (const float*)d_in[19];
  const float* scale_w = (const float*)d_in[20];
  const float* scale_b = (const float*)d_in[21];
  float* out = (float*)d_out;

  // workspace (all f32, ~30.4 MB):
  // [x 3MB][xz 12MB (hosts pbuf 6MB)][xn 3MB][xc 6MB][xBC 0.25MB][dt/y 6MB]
  float* x    = (float*)d_ws;                 // M*D
  float* xz   = x   + (size_t)M * D;          // M*1536
  float* pbuf = xz;                           // M*768 (dead before xz written)
  float* xn   = xz  + (size_t)M * TWO_E;      // M*D
  float* xc   = xn  + (size_t)M * D;          // M*E
  float* xBC  = xc  + (size_t)M * E;          // M*32
  float* dtb  = xBC + (size_t)M * 32;         // M*E (aliased as y)
  float* ybuf = dtb;

  patchify_kernel<<<(M * 768 + 255) / 256, 256, 0, stream>>>(px, pbuf);
  gemm_kernel<64, 4, 1><<<dim3(D / 64, M / 64), 256, 0, stream>>>(
      pbuf, 768, 768, patch_w, patch_b, x, pos, D);

  for (int l = 0; l < L; l++){
    layernorm_kernel<<<M / 4, 256, 0, stream>>>(x, norm_w + l * D, norm_b + l * D, xn);
    gemm_kernel<64, 4, 0><<<dim3(TWO_E / 64, M / 64), 256, 0, stream>>>(
        xn, D, D, in_w + (size_t)l * TWO_E * D, in_b + l * TWO_E, xz, nullptr, TWO_E);
    conv_silu_kernel<<<(M * E + 255) / 256, 256, 0, stream>>>(
        xz, conv_w + (size_t)l * E * 4, conv_b + l * E, xc);
    gemm_kernel<32, 2, 0><<<dim3(1, M / 64), 256, 0, stream>>>(
        xc, E, E, xp_w + (size_t)l * 32 * E, xp_b + l * 32, xBC, nullptr, 32);
    gemm_kernel<64, 4, 3><<<dim3(E / 64, M / 64), 256, 0, stream>>>(
        xBC, 32, 16, dt_w + (size_t)l * E * S, dt_b + l * E, dtb, nullptr, E);
    scan_kernel<<<(Bz * E) / 16, 256, 0, stream>>>(
        dtb, xc, xz, xBC, Aab + (size_t)l * E * S, Dp + l * E, ybuf);
    gemm_kernel<64, 4, 2><<<dim3(D / 64, M / 64), 256, 0, stream>>>(
        ybuf, E, E, out_w + (size_t)l * D * E, out_b + l * D, x, nullptr, D);
    if (l % 4 == 0 && l / 4 < 3){
      int j = l / 4;
      gemm_kernel<64, 4, 0><<<dim3(D / 64, M / 64), 256, 0, stream>>>(
          x, D, D, scale_w + (size_t)j * D * D, scale_b + j * D,
          out + (size_t)(1 + j) * M * D, nullptr, D);
    }
  }
  layernorm_kernel<<<M / 4, 256, 0, stream>>>(x, fnorm_w, fnorm_b, out);
}

// Round 5
// 3283.118 us; speedup vs baseline: 3.7592x; 3.7592x over previous
//
#include <hip/hip_runtime.h>
#include <hip/hip_bf16.h>

// problem sizes
constexpr int Bz = 2, IMG = 512, Pp = 16, D = 384, E = 768, S = 16, L = 12;
constexpr int G = IMG / Pp;          // 32
constexpr int Np = G * G;            // 1024 patches
constexpr int M = Bz * Np;           // 2048 rows
constexpr int TWO_E = 2 * E;         // 1536

// ---------------- patchify: pixels(f32) -> A matrix (M x 768) f32 ----------------
__global__ void patchify_kernel(const float* __restrict__ px, float* __restrict__ out){
  int idx = blockIdx.x * 256 + threadIdx.x;     // m*768 + k
  if (idx >= M * 768) return;
  int k = idx % 768, m = idx / 768;
  int b = m / Np, n = m % Np;
  int gy = n / G, gx = n % G;
  int c = k / (Pp * Pp), r = k % (Pp * Pp);
  int py = r / Pp, pxi = r % Pp;
  size_t src = ((size_t)(b * 3 + c) * IMG + gy * Pp + py) * IMG + gx * Pp + pxi;
  out[idx] = px[src];
}

// ---------------- layernorm over D=384 (f32 -> f32), one wave per row ----------------
__global__ __launch_bounds__(256)
void layernorm_kernel(const float* __restrict__ x, const float* __restrict__ w,
                      const float* __restrict__ bb, float* __restrict__ outf){
  int wave = threadIdx.x >> 6;
  int lane = threadIdx.x & 63;
  int row = blockIdx.x * 4 + wave;
  const float* xr = x + (size_t)row * D;
  float v[6];
  float s = 0.f, sq = 0.f;
  #pragma unroll
  for (int i = 0; i < 6; i++){ v[i] = xr[lane + 64 * i]; s += v[i]; sq += v[i] * v[i]; }
  #pragma unroll
  for (int off = 32; off; off >>= 1){ s += __shfl_xor(s, off); sq += __shfl_xor(sq, off); }
  float mean = s * (1.f / D);
  float var  = sq * (1.f / D) - mean * mean;
  float inv  = 1.0f / sqrtf(var + 1e-5f);
  #pragma unroll
  for (int i = 0; i < 6; i++){
    int c = lane + 64 * i;
    outf[(size_t)row * D + c] = (v[i] - mean) * inv * w[c] + bb[c];
  }
}

// ---------------- tiled GEMM: C[M,N] = A[M,K](f32) * W[N,K](f32)^T + bias ----------------
// EPI: 0 = bias -> C[m*ncols+n]
//      1 = +pos -> C
//      2 = in-place residual add into C
//      4 = in-proj split: n<E -> C[m*E+n] (x_main); n>=E -> C2[(n-E)*M+m] = silu(v) (z transposed)
//      5 = dt: softplus+clip -> transposed C[n*M+m]
template<int BN, int TN, int EPI>
__global__ __launch_bounds__(256)
void gemm_kernel(const float* __restrict__ A, int lda, int K,
                 const float* __restrict__ W, const float* __restrict__ bias,
                 float* __restrict__ C, float* __restrict__ C2,
                 const float* __restrict__ pos, int ncols){
  __shared__ float As[16][64 + 1];
  __shared__ float Ws[16][BN + 1];
  int tid = threadIdx.x;
  int tx = tid & 15, ty = tid >> 4;
  int m0 = blockIdx.y * 64, n0 = blockIdx.x * BN;
  float acc[4][TN];
  #pragma unroll
  for (int i = 0; i < 4; i++)
    #pragma unroll
    for (int j = 0; j < TN; j++) acc[i][j] = 0.f;

  for (int kt = 0; kt < K; kt += 16){
    { // A tile 64x16
      int r = tid >> 2, kk = (tid & 3) << 2;
      const float* ap = A + (size_t)(m0 + r) * lda + kt + kk;
      As[kk + 0][r] = ap[0]; As[kk + 1][r] = ap[1];
      As[kk + 2][r] = ap[2]; As[kk + 3][r] = ap[3];
    }
    if (BN == 64 || tid < BN * 4){ // W tile BNx16
      int c = tid >> 2, kk = (tid & 3) << 2;
      const float* wp = W + (size_t)(n0 + c) * K + kt + kk;
      Ws[kk + 0][c] = wp[0]; Ws[kk + 1][c] = wp[1];
      Ws[kk + 2][c] = wp[2]; Ws[kk + 3][c] = wp[3];
    }
    __syncthreads();
    #pragma unroll
    for (int k = 0; k < 16; k++){
      float a[4], w[TN];
      #pragma unroll
      for (int i = 0; i < 4; i++) a[i] = As[k][ty * 4 + i];
      #pragma unroll
      for (int j = 0; j < TN; j++) w[j] = Ws[k][tx * TN + j];
      #pragma unroll
      for (int i = 0; i < 4; i++)
        #pragma unroll
        for (int j = 0; j < TN; j++) acc[i][j] += a[i] * w[j];
    }
    __syncthreads();
  }

  #pragma unroll
  for (int i = 0; i < 4; i++){
    int m = m0 + ty * 4 + i;
    #pragma unroll
    for (int j = 0; j < TN; j++){
      int n = n0 + tx * TN + j;
      float v = acc[i][j] + bias[n];
      if constexpr (EPI == 0){ C[(size_t)m * ncols + n] = v; }
      if constexpr (EPI == 1){ v += pos[(size_t)(m & (Np - 1)) * ncols + n];
                               C[(size_t)m * ncols + n] = v; }
      if constexpr (EPI == 2){ v += C[(size_t)m * ncols + n];
                               C[(size_t)m * ncols + n] = v; }
      if constexpr (EPI == 4){
        if (n < E) C[(size_t)m * E + n] = v;
        else {
          float sig = 1.f / (1.f + expf(-v));
          C2[(size_t)(n - E) * M + m] = v * sig;
        }
      }
      if constexpr (EPI == 5){
        v = (v > 15.f) ? v : log1pf(expf(v));
        v = fminf(fmaxf(v, 1e-4f), 1.0f);
        C[(size_t)n * M + m] = v;
      }
    }
  }
}

// ---------------- depthwise causal conv (K=4) + SiLU, f32 ----------------
// reads x_main [m][E], writes xc [m][E]
__global__ void conv_silu_kernel(const float* __restrict__ xm, const float* __restrict__ cw,
                                 const float* __restrict__ cb, float* __restrict__ xc){
  int idx = blockIdx.x * 256 + threadIdx.x;     // m*E + e
  if (idx >= M * E) return;
  int e = idx % E, m = idx / E;
  int n = m & (Np - 1);
  float acc = cb[e];
  #pragma unroll
  for (int kk = 0; kk < 4; kk++){
    int j = n - 3 + kk;
    if (j >= 0) acc += cw[e * 4 + kk] * xm[(size_t)(m - 3 + kk) * E + e];
  }
  float sig = 1.f / (1.f + expf(-acc));
  xc[idx] = acc * sig;
}

// ---------------- chunked selective scan ----------------
// one block per (b,e) row; 16 groups x 16 lanes; chunk = 64 steps.
// phase 1: local scan (h=0) -> yloc, per-chunk (prodA, h_final)
// phase 2: 16-step sequential combine -> carry-in Hin per chunk
// phase 3: correction Q = dA*Q (Q0 = Hin), y = (yloc + Q.xC) * silu(z)
__global__ __launch_bounds__(256)
void scan_kernel(const float* __restrict__ dtt, const float* __restrict__ xc,
                 const float* __restrict__ zst, const float* __restrict__ xBC,
                 const float* __restrict__ Aptr, const float* __restrict__ Dp,
                 float* __restrict__ y){
  __shared__ float yloc[1024];
  __shared__ float hloc[16][16], prodA[16][16], Hin[16][16];
  const int t = threadIdx.x, g = t >> 4, s = t & 15;
  const int r = blockIdx.x, b = r / E, e = r % E;
  const float a   = Aptr[e * S + s];
  const float dpe = Dp[e];
  const float* dtp = dtt + (size_t)e * M + b * Np;   // [n]
  const float* zsp = zst + (size_t)e * M + b * Np;   // [n], pre-silu'd
  const int n0 = g * 64;
  const int mbase = b * Np + n0;

  float h = 0.f, P = 1.f;
  for (int i = 0; i < 64; i++){
    int n = n0 + i, m = mbase + i;
    float dt  = dtp[n];
    float xcv = xc[(size_t)m * E + e];
    float xb  = xBC[m * 32 + s];
    float xcs = xBC[m * 32 + 16 + s];
    float dA = __expf(fmaxf(dt * a, -20.f));
    h = dA * h + xb * xcv;
    P *= dA;
    float p = h * xcs;
    p += __shfl_xor(p, 8); p += __shfl_xor(p, 4);
    p += __shfl_xor(p, 2); p += __shfl_xor(p, 1);
    if (s == 0) yloc[n0 + i] = p + dpe * xcv;
  }
  hloc[g][s] = h; prodA[g][s] = P;
  __syncthreads();
  if (t < 16){
    float H = 0.f;
    #pragma unroll
    for (int g2 = 0; g2 < 16; g2++){
      Hin[g2][t] = H;
      H = prodA[g2][t] * H + hloc[g2][t];
    }
  }
  __syncthreads();
  float Q = Hin[g][s];
  for (int i = 0; i < 64; i++){
    int n = n0 + i, m = mbase + i;
    float dt  = dtp[n];
    float xcs = xBC[m * 32 + 16 + s];
    float dA = __expf(fmaxf(dt * a, -20.f));
    Q *= dA;
    float p = Q * xcs;
    p += __shfl_xor(p, 8); p += __shfl_xor(p, 4);
    p += __shfl_xor(p, 2); p += __shfl_xor(p, 1);
    if (s == 0)
      y[(size_t)m * E + e] = (yloc[n0 + i] + p) * zsp[n];
  }
}

extern "C" void kernel_launch(void* const* d_in, const int* in_sizes, int n_in,
                              void* d_out, int out_size, void* d_ws, size_t ws_size,
                              hipStream_t stream){
  const float* px      = (const float*)d_in[0];
  const float* patch_w = (const float*)d_in[1];
  const float* patch_b = (const float*)d_in[2];
  const float* pos     = (const float*)d_in[3];
  const float* norm_w  = (const float*)d_in[4];
  const float* norm_b  = (const float*)d_in[5];
  const float* in_w    = (const float*)d_in[6];
  const float* in_b    = (const float*)d_in[7];
  const float* conv_w  = (const float*)d_in[8];
  const float* conv_b  = (const float*)d_in[9];
  const float* xp_w    = (const float*)d_in[10];
  const float* xp_b    = (const float*)d_in[11];
  const float* dt_w    = (const float*)d_in[12];
  const float* dt_b    = (const float*)d_in[13];
  const float* Aab     = (const float*)d_in[14];
  const float* Dp      = (const float*)d_in[15];
  const float* out_w   = (const float*)d_in[16];
  const float* out_b   = (const float*)d_in[17];
  const float* fnorm_w = (const float*)d_in[18];
  const float* fnorm_b = (const float*)d_in[19];
  const float* scale_w = (const float*)d_in[20];
  const float* scale_b = (const float*)d_in[21];
  float* out = (float*)d_out;

  // workspace (all f32, 30.25 MB):
  // [x 3MB][xzm 6MB (hosts pbuf; y aliases after conv)][zst 6MB][xn 3MB]
  // [xc 6MB][xBC 0.25MB][dtt 6MB]
  float* x    = (float*)d_ws;                 // M*D
  float* xzm  = x    + (size_t)M * D;         // M*E   x_main (row-major)
  float* pbuf = xzm;                          // M*768 (dead before xzm written)
  float* ybuf = xzm;                          // y overwrites x_main after conv
  float* zst  = xzm  + (size_t)M * E;         // E*M   silu(z) transposed
  float* xn   = zst  + (size_t)M * E;         // M*D
  float* xc   = xn   + (size_t)M * D;         // M*E
  float* xBC  = xc   + (size_t)M * E;         // M*32
  float* dtt  = xBC  + (size_t)M * 32;        // E*M   dt transposed

  patchify_kernel<<<(M * 768 + 255) / 256, 256, 0, stream>>>(px, pbuf);
  gemm_kernel<64, 4, 1><<<dim3(D / 64, M / 64), 256, 0, stream>>>(
      pbuf, 768, 768, patch_w, patch_b, x, nullptr, pos, D);

  for (int l = 0; l < L; l++){
    layernorm_kernel<<<M / 4, 256, 0, stream>>>(x, norm_w + l * D, norm_b + l * D, xn);
    gemm_kernel<64, 4, 4><<<dim3(TWO_E / 64, M / 64), 256, 0, stream>>>(
        xn, D, D, in_w + (size_t)l * TWO_E * D, in_b + l * TWO_E, xzm, zst, nullptr, TWO_E);
    conv_silu_kernel<<<(M * E + 255) / 256, 256, 0, stream>>>(
        xzm, conv_w + (size_t)l * E * 4, conv_b + l * E, xc);
    gemm_kernel<32, 2, 0><<<dim3(1, M / 64), 256, 0, stream>>>(
        xc, E, E, xp_w + (size_t)l * 32 * E, xp_b + l * 32, xBC, nullptr, nullptr, 32);
    gemm_kernel<64, 4, 5><<<dim3(E / 64, M / 64), 256, 0, stream>>>(
        xBC, 32, 16, dt_w + (size_t)l * E * S, dt_b + l * E, dtt, nullptr, nullptr, E);
    scan_kernel<<<Bz * E, 256, 0, stream>>>(
        dtt, xc, zst, xBC, Aab + (size_t)l * E * S, Dp + l * E, ybuf);
    gemm_kernel<64, 4, 2><<<dim3(D / 64, M / 64), 256, 0, stream>>>(
        ybuf, E, E, out_w + (size_t)l * D * E, out_b + l * D, x, nullptr, nullptr, D);
    if (l % 4 == 0 && l / 4 < 3){
      int j = l / 4;
      gemm_kernel<64, 4, 0><<<dim3(D / 64, M / 64), 256, 0, stream>>>(
          x, D, D, scale_w + (size_t)j * D * D, scale_b + j * D,
          out + (size_t)(1 + j) * M * D, nullptr, nullptr, D);
    }
  }
  layernorm_kernel<<<M / 4, 256, 0, stream>>>(x, fnorm_w, fnorm_b, out);
}

// Round 6
// 3089.320 us; speedup vs baseline: 3.9950x; 1.0627x over previous
//
#include <hip/hip_runtime.h>
#include <hip/hip_bf16.h>

// problem sizes
constexpr int Bz = 2, IMG = 512, Pp = 16, D = 384, E = 768, S = 16, L = 12;
constexpr int G = IMG / Pp;          // 32
constexpr int Np = G * G;            // 1024 patches
constexpr int M = Bz * Np;           // 2048 rows
constexpr int TWO_E = 2 * E;         // 1536

typedef short bf16x8 __attribute__((ext_vector_type(8)));
typedef float fx4    __attribute__((ext_vector_type(4)));

static __device__ __forceinline__ unsigned short f2bf(float f){
  unsigned int u = __float_as_uint(f);
  u = (u + 0x7FFFu + ((u >> 16) & 1u)) >> 16;       // RN-even
  return (unsigned short)u;
}
static __device__ __forceinline__ float bf2f(unsigned short h){
  return __uint_as_float(((unsigned int)h) << 16);
}

// ---------------- patchify: pixels(f32) -> A matrix (M x 768) f32 ----------------
__global__ void patchify_kernel(const float* __restrict__ px, float* __restrict__ out){
  int idx = blockIdx.x * 256 + threadIdx.x;     // m*768 + k
  if (idx >= M * 768) return;
  int k = idx % 768, m = idx / 768;
  int b = m / Np, n = m % Np;
  int gy = n / G, gx = n % G;
  int c = k / (Pp * Pp), r = k % (Pp * Pp);
  int py = r / Pp, pxi = r % Pp;
  size_t src = ((size_t)(b * 3 + c) * IMG + gy * Pp + py) * IMG + gx * Pp + pxi;
  out[idx] = px[src];
}

// ---------------- layernorm over D=384 (f32 -> f32), one wave per row ----------------
__global__ __launch_bounds__(256)
void layernorm_kernel(const float* __restrict__ x, const float* __restrict__ w,
                      const float* __restrict__ bb, float* __restrict__ outf){
  int wave = threadIdx.x >> 6;
  int lane = threadIdx.x & 63;
  int row = blockIdx.x * 4 + wave;
  const float* xr = x + (size_t)row * D;
  float v[6];
  float s = 0.f, sq = 0.f;
  #pragma unroll
  for (int i = 0; i < 6; i++){ v[i] = xr[lane + 64 * i]; s += v[i]; sq += v[i] * v[i]; }
  #pragma unroll
  for (int off = 32; off; off >>= 1){ s += __shfl_xor(s, off); sq += __shfl_xor(sq, off); }
  float mean = s * (1.f / D);
  float var  = sq * (1.f / D) - mean * mean;
  float inv  = 1.0f / sqrtf(var + 1e-5f);
  #pragma unroll
  for (int i = 0; i < 6; i++){
    int c = lane + 64 * i;
    outf[(size_t)row * D + c] = (v[i] - mean) * inv * w[c] + bb[c];
  }
}

// ---------------- MFMA GEMM (bf16 hi/lo split = fp32-quality) ----------------
// C[M,N] = A[M,K](f32) * W[N,K](f32)^T + bias.  BM=64, BN=128, BK=32.
// 4 waves; wave computes 64(m) x 32(n) via 4x2 tiles of 16x16x32, 3 MFMA each.
// EPI: 0 = bias -> C[m*ncols+n]
//      1 = +pos -> C
//      2 = in-place residual add into C
//      4 = in-proj split: n<E -> C[m*E+n]; n>=E -> C2[(n-E)*M+m] = silu(v)
template<int EPI>
__global__ __launch_bounds__(256)
void gemm_mfma(const float* __restrict__ A, int lda, int K,
               const float* __restrict__ W, const float* __restrict__ bias,
               float* __restrict__ C, float* __restrict__ C2,
               const float* __restrict__ pos, int ncols){
  constexpr int BKp = 40;                      // row stride (bf16) pad: 32+8
  __shared__ __align__(16) unsigned short Ah[64 * BKp],  Al[64 * BKp];
  __shared__ __align__(16) unsigned short Wh[128 * BKp], Wl[128 * BKp];
  const int t = threadIdx.x, wid = t >> 6, lane = t & 63;
  const int m0 = blockIdx.y * 64, n0 = blockIdx.x * 128;

  fx4 acc[4][2];
  #pragma unroll
  for (int a = 0; a < 4; a++)
    #pragma unroll
    for (int b = 0; b < 2; b++)
      #pragma unroll
      for (int i = 0; i < 4; i++) acc[a][b][i] = 0.f;

  for (int kt = 0; kt < K; kt += 32){
    #pragma unroll
    for (int q = t; q < 512; q += 256){        // A tile 64x32 f32 -> hi/lo bf16
      int r = q >> 3, kp = (q & 7) << 2;
      const float4 v = *(const float4*)(A + (size_t)(m0 + r) * lda + kt + kp);
      int o = r * BKp + kp;
      float f[4] = {v.x, v.y, v.z, v.w};
      #pragma unroll
      for (int i = 0; i < 4; i++){
        unsigned short h = f2bf(f[i]);
        Ah[o + i] = h; Al[o + i] = f2bf(f[i] - bf2f(h));
      }
    }
    #pragma unroll
    for (int q = t; q < 1024; q += 256){       // W tile 128x32
      int r = q >> 3, kp = (q & 7) << 2;
      const float4 v = *(const float4*)(W + (size_t)(n0 + r) * K + kt + kp);
      int o = r * BKp + kp;
      float f[4] = {v.x, v.y, v.z, v.w};
      #pragma unroll
      for (int i = 0; i < 4; i++){
        unsigned short h = f2bf(f[i]);
        Wh[o + i] = h; Wl[o + i] = f2bf(f[i] - bf2f(h));
      }
    }
    __syncthreads();
    const int row = lane & 15, kq = lane >> 4;
    bf16x8 ah[4], al[4], bh[2], bl[2];
    #pragma unroll
    for (int tm = 0; tm < 4; tm++){
      ah[tm] = *(const bf16x8*)&Ah[(tm * 16 + row) * BKp + kq * 8];
      al[tm] = *(const bf16x8*)&Al[(tm * 16 + row) * BKp + kq * 8];
    }
    #pragma unroll
    for (int tn = 0; tn < 2; tn++){
      bh[tn] = *(const bf16x8*)&Wh[(wid * 32 + tn * 16 + row) * BKp + kq * 8];
      bl[tn] = *(const bf16x8*)&Wl[(wid * 32 + tn * 16 + row) * BKp + kq * 8];
    }
    #pragma unroll
    for (int tm = 0; tm < 4; tm++)
      #pragma unroll
      for (int tn = 0; tn < 2; tn++){
        acc[tm][tn] = __builtin_amdgcn_mfma_f32_16x16x32_bf16(ah[tm], bh[tn], acc[tm][tn], 0, 0, 0);
        acc[tm][tn] = __builtin_amdgcn_mfma_f32_16x16x32_bf16(ah[tm], bl[tn], acc[tm][tn], 0, 0, 0);
        acc[tm][tn] = __builtin_amdgcn_mfma_f32_16x16x32_bf16(al[tm], bh[tn], acc[tm][tn], 0, 0, 0);
      }
    __syncthreads();
  }

  const int row4 = (lane >> 4) * 4, coln = lane & 15;
  #pragma unroll
  for (int tm = 0; tm < 4; tm++)
    #pragma unroll
    for (int tn = 0; tn < 2; tn++)
      #pragma unroll
      for (int i = 0; i < 4; i++){
        int m = m0 + tm * 16 + row4 + i;
        int n = n0 + wid * 32 + tn * 16 + coln;
        float v = acc[tm][tn][i] + bias[n];
        if constexpr (EPI == 0){ C[(size_t)m * ncols + n] = v; }
        if constexpr (EPI == 1){ v += pos[(size_t)(m & (Np - 1)) * ncols + n];
                                 C[(size_t)m * ncols + n] = v; }
        if constexpr (EPI == 2){ v += C[(size_t)m * ncols + n];
                                 C[(size_t)m * ncols + n] = v; }
        if constexpr (EPI == 4){
          if (n < E) C[(size_t)m * E + n] = v;
          else {
            float sig = 1.f / (1.f + expf(-v));
            C2[(size_t)(n - E) * M + m] = v * sig;
          }
        }
      }
}

// ---------------- vector GEMM for dt (K=16): softplus+clip -> transposed C[n*M+m] ----------------
__global__ __launch_bounds__(256)
void gemm_dt(const float* __restrict__ A, const float* __restrict__ W,
             const float* __restrict__ bias, float* __restrict__ C){
  __shared__ float As[16][64 + 1];
  __shared__ float Ws[16][64 + 1];
  int tid = threadIdx.x;
  int tx = tid & 15, ty = tid >> 4;
  int m0 = blockIdx.y * 64, n0 = blockIdx.x * 64;
  float acc[4][4];
  #pragma unroll
  for (int i = 0; i < 4; i++)
    #pragma unroll
    for (int j = 0; j < 4; j++) acc[i][j] = 0.f;
  { // single K-block of 16 (A lda=32, W ldw=16)
    int r = tid >> 2, kk = (tid & 3) << 2;
    const float* ap = A + (size_t)(m0 + r) * 32 + kk;
    As[kk + 0][r] = ap[0]; As[kk + 1][r] = ap[1];
    As[kk + 2][r] = ap[2]; As[kk + 3][r] = ap[3];
    const float* wp = W + (size_t)(n0 + r) * 16 + kk;
    Ws[kk + 0][r] = wp[0]; Ws[kk + 1][r] = wp[1];
    Ws[kk + 2][r] = wp[2]; Ws[kk + 3][r] = wp[3];
  }
  __syncthreads();
  #pragma unroll
  for (int k = 0; k < 16; k++){
    float a[4], w[4];
    #pragma unroll
    for (int i = 0; i < 4; i++) a[i] = As[k][ty * 4 + i];
    #pragma unroll
    for (int j = 0; j < 4; j++) w[j] = Ws[k][tx * 4 + j];
    #pragma unroll
    for (int i = 0; i < 4; i++)
      #pragma unroll
      for (int j = 0; j < 4; j++) acc[i][j] += a[i] * w[j];
  }
  #pragma unroll
  for (int i = 0; i < 4; i++){
    int m = m0 + ty * 4 + i;
    #pragma unroll
    for (int j = 0; j < 4; j++){
      int n = n0 + tx * 4 + j;
      float v = acc[i][j] + bias[n];
      v = (v > 15.f) ? v : log1pf(expf(v));
      v = fminf(fmaxf(v, 1e-4f), 1.0f);
      C[(size_t)n * M + m] = v;
    }
  }
}

// ---------------- xp GEMM: xBC[M,32] += xc[M,768] * xp_w[32,768]^T, K-split x4 ----------------
__global__ __launch_bounds__(256)
void gemm_xp(const float* __restrict__ A, const float* __restrict__ W,
             const float* __restrict__ bias, float* __restrict__ C){
  __shared__ float As[16][64 + 1];
  __shared__ float Ws[16][32 + 1];
  int tid = threadIdx.x;
  int tx = tid & 15, ty = tid >> 4;
  int m0 = blockIdx.y * 64, kb = blockIdx.x * 192;
  float acc[4][2];
  #pragma unroll
  for (int i = 0; i < 4; i++){ acc[i][0] = 0.f; acc[i][1] = 0.f; }
  for (int kt = kb; kt < kb + 192; kt += 16){
    {
      int r = tid >> 2, kk = (tid & 3) << 2;
      const float* ap = A + (size_t)(m0 + r) * E + kt + kk;
      As[kk + 0][r] = ap[0]; As[kk + 1][r] = ap[1];
      As[kk + 2][r] = ap[2]; As[kk + 3][r] = ap[3];
    }
    if (tid < 128){
      int c = tid >> 2, kk = (tid & 3) << 2;
      const float* wp = W + (size_t)c * E + kt + kk;
      Ws[kk + 0][c] = wp[0]; Ws[kk + 1][c] = wp[1];
      Ws[kk + 2][c] = wp[2]; Ws[kk + 3][c] = wp[3];
    }
    __syncthreads();
    #pragma unroll
    for (int k = 0; k < 16; k++){
      float a[4], w[2];
      #pragma unroll
      for (int i = 0; i < 4; i++) a[i] = As[k][ty * 4 + i];
      w[0] = Ws[k][tx * 2]; w[1] = Ws[k][tx * 2 + 1];
      #pragma unroll
      for (int i = 0; i < 4; i++){ acc[i][0] += a[i] * w[0]; acc[i][1] += a[i] * w[1]; }
    }
    __syncthreads();
  }
  #pragma unroll
  for (int i = 0; i < 4; i++){
    int m = m0 + ty * 4 + i;
    #pragma unroll
    for (int j = 0; j < 2; j++){
      int n = tx * 2 + j;
      float v = acc[i][j];
      if (blockIdx.x == 0) v += bias[n];
      atomicAdd(&C[(size_t)m * 32 + n], v);
    }
  }
}

// ---------------- depthwise causal conv (K=4) + SiLU, f32 ----------------
__global__ void conv_silu_kernel(const float* __restrict__ xm, const float* __restrict__ cw,
                                 const float* __restrict__ cb, float* __restrict__ xc){
  int idx = blockIdx.x * 256 + threadIdx.x;     // m*E + e
  if (idx >= M * E) return;
  int e = idx % E, m = idx / E;
  int n = m & (Np - 1);
  float acc = cb[e];
  #pragma unroll
  for (int kk = 0; kk < 4; kk++){
    int j = n - 3 + kk;
    if (j >= 0) acc += cw[e * 4 + kk] * xm[(size_t)(m - 3 + kk) * E + e];
  }
  float sig = 1.f / (1.f + expf(-acc));
  xc[idx] = acc * sig;
}

// ---------------- chunked selective scan (as R5) ----------------
__global__ __launch_bounds__(256)
void scan_kernel(const float* __restrict__ dtt, const float* __restrict__ xc,
                 const float* __restrict__ zst, const float* __restrict__ xBC,
                 const float* __restrict__ Aptr, const float* __restrict__ Dp,
                 float* __restrict__ y){
  __shared__ float yloc[1024];
  __shared__ float hloc[16][16], prodA[16][16], Hin[16][16];
  const int t = threadIdx.x, g = t >> 4, s = t & 15;
  const int r = blockIdx.x, b = r / E, e = r % E;
  const float a   = Aptr[e * S + s];
  const float dpe = Dp[e];
  const float* dtp = dtt + (size_t)e * M + b * Np;
  const float* zsp = zst + (size_t)e * M + b * Np;
  const int n0 = g * 64;
  const int mbase = b * Np + n0;

  float h = 0.f, P = 1.f;
  for (int i = 0; i < 64; i++){
    int n = n0 + i, m = mbase + i;
    float dt  = dtp[n];
    float xcv = xc[(size_t)m * E + e];
    float xb  = xBC[m * 32 + s];
    float xcs = xBC[m * 32 + 16 + s];
    float dA = __expf(fmaxf(dt * a, -20.f));
    h = dA * h + xb * xcv;
    P *= dA;
    float p = h * xcs;
    p += __shfl_xor(p, 8); p += __shfl_xor(p, 4);
    p += __shfl_xor(p, 2); p += __shfl_xor(p, 1);
    if (s == 0) yloc[n0 + i] = p + dpe * xcv;
  }
  hloc[g][s] = h; prodA[g][s] = P;
  __syncthreads();
  if (t < 16){
    float H = 0.f;
    #pragma unroll
    for (int g2 = 0; g2 < 16; g2++){
      Hin[g2][t] = H;
      H = prodA[g2][t] * H + hloc[g2][t];
    }
  }
  __syncthreads();
  float Q = Hin[g][s];
  for (int i = 0; i < 64; i++){
    int n = n0 + i, m = mbase + i;
    float dt  = dtp[n];
    float xcs = xBC[m * 32 + 16 + s];
    float dA = __expf(fmaxf(dt * a, -20.f));
    Q *= dA;
    float p = Q * xcs;
    p += __shfl_xor(p, 8); p += __shfl_xor(p, 4);
    p += __shfl_xor(p, 2); p += __shfl_xor(p, 1);
    if (s == 0)
      y[(size_t)m * E + e] = (yloc[n0 + i] + p) * zsp[n];
  }
}

extern "C" void kernel_launch(void* const* d_in, const int* in_sizes, int n_in,
                              void* d_out, int out_size, void* d_ws, size_t ws_size,
                              hipStream_t stream){
  const float* px      = (const float*)d_in[0];
  const float* patch_w = (const float*)d_in[1];
  const float* patch_b = (const float*)d_in[2];
  const float* pos     = (const float*)d_in[3];
  const float* norm_w  = (const float*)d_in[4];
  const float* norm_b  = (const float*)d_in[5];
  const float* in_w    = (const float*)d_in[6];
  const float* in_b    = (const float*)d_in[7];
  const float* conv_w  = (const float*)d_in[8];
  const float* conv_b  = (const float*)d_in[9];
  const float* xp_w    = (const float*)d_in[10];
  const float* xp_b    = (const float*)d_in[11];
  const float* dt_w    = (const float*)d_in[12];
  const float* dt_b    = (const float*)d_in[13];
  const float* Aab     = (const float*)d_in[14];
  const float* Dp      = (const float*)d_in[15];
  const float* out_w   = (const float*)d_in[16];
  const float* out_b   = (const float*)d_in[17];
  const float* fnorm_w = (const float*)d_in[18];
  const float* fnorm_b = (const float*)d_in[19];
  const float* scale_w = (const float*)d_in[20];
  const float* scale_b = (const float*)d_in[21];
  float* out = (float*)d_out;

  // workspace (all f32, 30.25 MB)
  float* x    = (float*)d_ws;                 // M*D
  float* xzm  = x    + (size_t)M * D;         // M*E   x_main (row-major)
  float* pbuf = xzm;                          // M*768 (dead before xzm written)
  float* ybuf = xzm;                          // y overwrites x_main after conv
  float* zst  = xzm  + (size_t)M * E;         // E*M   silu(z) transposed
  float* xn   = zst  + (size_t)M * E;         // M*D
  float* xc   = xn   + (size_t)M * D;         // M*E
  float* xBC  = xc   + (size_t)M * E;         // M*32
  float* dtt  = xBC  + (size_t)M * 32;        // E*M   dt transposed

  patchify_kernel<<<(M * 768 + 255) / 256, 256, 0, stream>>>(px, pbuf);
  gemm_mfma<1><<<dim3(D / 128, M / 64), 256, 0, stream>>>(
      pbuf, 768, 768, patch_w, patch_b, x, nullptr, pos, D);

  for (int l = 0; l < L; l++){
    layernorm_kernel<<<M / 4, 256, 0, stream>>>(x, norm_w + l * D, norm_b + l * D, xn);
    gemm_mfma<4><<<dim3(TWO_E / 128, M / 64), 256, 0, stream>>>(
        xn, D, D, in_w + (size_t)l * TWO_E * D, in_b + l * TWO_E, xzm, zst, nullptr, TWO_E);
    conv_silu_kernel<<<(M * E + 255) / 256, 256, 0, stream>>>(
        xzm, conv_w + (size_t)l * E * 4, conv_b + l * E, xc);
    hipMemsetAsync(xBC, 0, (size_t)M * 32 * sizeof(float), stream);
    gemm_xp<<<dim3(4, M / 64), 256, 0, stream>>>(
        xc, xp_w + (size_t)l * 32 * E, xp_b + l * 32, xBC);
    gemm_dt<<<dim3(E / 64, M / 64), 256, 0, stream>>>(
        xBC, dt_w + (size_t)l * E * S, dt_b + l * E, dtt);
    scan_kernel<<<Bz * E, 256, 0, stream>>>(
        dtt, xc, zst, xBC, Aab + (size_t)l * E * S, Dp + l * E, ybuf);
    gemm_mfma<2><<<dim3(D / 128, M / 64), 256, 0, stream>>>(
        ybuf, E, E, out_w + (size_t)l * D * E, out_b + l * D, x, nullptr, nullptr, D);
    if (l % 4 == 0 && l / 4 < 3){
      int j = l / 4;
      gemm_mfma<0><<<dim3(D / 128, M / 64), 256, 0, stream>>>(
          x, D, D, scale_w + (size_t)j * D * D, scale_b + j * D,
          out + (size_t)(1 + j) * M * D, nullptr, nullptr, D);
    }
  }
  layernorm_kernel<<<M / 4, 256, 0, stream>>>(x, fnorm_w, fnorm_b, out);
}

// Round 7
// 2352.965 us; speedup vs baseline: 5.2453x; 1.3129x over previous
//
#include <hip/hip_runtime.h>
#include <hip/hip_bf16.h>

// problem sizes
constexpr int Bz = 2, IMG = 512, Pp = 16, D = 384, E = 768, S = 16, L = 12;
constexpr int G = IMG / Pp;          // 32
constexpr int Np = G * G;            // 1024 patches
constexpr int M = Bz * Np;           // 2048 rows
constexpr int TWO_E = 2 * E;         // 1536

typedef short bf16x8 __attribute__((ext_vector_type(8)));
typedef float fx4    __attribute__((ext_vector_type(4)));

static __device__ __forceinline__ unsigned short f2bf(float f){
  unsigned int u = __float_as_uint(f);
  u = (u + 0x7FFFu + ((u >> 16) & 1u)) >> 16;       // RN-even
  return (unsigned short)u;
}
static __device__ __forceinline__ float bf2f(unsigned short h){
  return __uint_as_float(((unsigned int)h) << 16);
}

// ---------------- converted-weight store (device globals; no ws, no hipMalloc) ----------------
constexpr size_t PW_N = (size_t)D * 768;            // 294,912
constexpr size_t IW_N = (size_t)L * TWO_E * D;      // 7,077,888
constexpr size_t OW_N = (size_t)L * D * E;          // 3,538,944
constexpr size_t SW_N = (size_t)3 * D * D;          // 442,368
__device__ short g_pw_h[PW_N], g_pw_l[PW_N];
__device__ short g_iw_h[IW_N], g_iw_l[IW_N];
__device__ short g_ow_h[OW_N], g_ow_l[OW_N];
__device__ short g_sw_h[SW_N], g_sw_l[SW_N];

template<int WSEL> __device__ __forceinline__ const short* wsel_h(){
  if constexpr (WSEL == 0) return g_pw_h;
  else if constexpr (WSEL == 1) return g_iw_h;
  else if constexpr (WSEL == 2) return g_ow_h;
  else return g_sw_h;
}
template<int WSEL> __device__ __forceinline__ const short* wsel_l(){
  if constexpr (WSEL == 0) return g_pw_l;
  else if constexpr (WSEL == 1) return g_iw_l;
  else if constexpr (WSEL == 2) return g_ow_l;
  else return g_sw_l;
}

__global__ void convw_kernel(const float* __restrict__ pw, const float* __restrict__ iw,
                             const float* __restrict__ ow, const float* __restrict__ sw){
  size_t i = (size_t)blockIdx.x * 256 + threadIdx.x;
  if (i >= PW_N + IW_N + OW_N + SW_N) return;
  const float* src; short *dh, *dl; size_t j = i;
  if (j < PW_N){ src = pw; dh = g_pw_h; dl = g_pw_l; }
  else if ((j -= PW_N) < IW_N){ src = iw; dh = g_iw_h; dl = g_iw_l; }
  else if ((j -= IW_N) < OW_N){ src = ow; dh = g_ow_h; dl = g_ow_l; }
  else { j -= OW_N; src = sw; dh = g_sw_h; dl = g_sw_l; }
  float f = src[j];
  unsigned short h = f2bf(f);
  dh[j] = (short)h; dl[j] = (short)f2bf(f - bf2f(h));
}

// ---------------- patchify: pixels(f32) -> hi/lo bf16 (M x 768) ----------------
__global__ void patchify_kernel(const float* __restrict__ px,
                                short* __restrict__ oh, short* __restrict__ ol){
  int idx = blockIdx.x * 256 + threadIdx.x;     // m*768 + k
  if (idx >= M * 768) return;
  int k = idx % 768, m = idx / 768;
  int b = m / Np, n = m % Np;
  int gy = n / G, gx = n % G;
  int c = k / (Pp * Pp), r = k % (Pp * Pp);
  int py = r / Pp, pxi = r % Pp;
  size_t src = ((size_t)(b * 3 + c) * IMG + gy * Pp + py) * IMG + gx * Pp + pxi;
  float f = px[src];
  unsigned short h = f2bf(f);
  oh[idx] = (short)h; ol[idx] = (short)f2bf(f - bf2f(h));
}

// ---------------- convert f32 -> hi/lo bf16 (for residual x before scale GEMM) ----------------
__global__ void convx_kernel(const float* __restrict__ x,
                             short* __restrict__ oh, short* __restrict__ ol){
  int idx = blockIdx.x * 256 + threadIdx.x;
  if (idx >= M * D) return;
  float f = x[idx];
  unsigned short h = f2bf(f);
  oh[idx] = (short)h; ol[idx] = (short)f2bf(f - bf2f(h));
}

// ---------------- layernorm over D=384: f32 in -> hi/lo bf16 out ----------------
__global__ __launch_bounds__(256)
void layernorm_bf(const float* __restrict__ x, const float* __restrict__ w,
                  const float* __restrict__ bb, short* __restrict__ oh,
                  short* __restrict__ ol){
  int wave = threadIdx.x >> 6;
  int lane = threadIdx.x & 63;
  int row = blockIdx.x * 4 + wave;
  const float* xr = x + (size_t)row * D;
  float v[6];
  float s = 0.f, sq = 0.f;
  #pragma unroll
  for (int i = 0; i < 6; i++){ v[i] = xr[lane + 64 * i]; s += v[i]; sq += v[i] * v[i]; }
  #pragma unroll
  for (int off = 32; off; off >>= 1){ s += __shfl_xor(s, off); sq += __shfl_xor(sq, off); }
  float mean = s * (1.f / D);
  float var  = sq * (1.f / D) - mean * mean;
  float inv  = 1.0f / sqrtf(var + 1e-5f);
  #pragma unroll
  for (int i = 0; i < 6; i++){
    int c = lane + 64 * i;
    float o = (v[i] - mean) * inv * w[c] + bb[c];
    unsigned short h = f2bf(o);
    oh[(size_t)row * D + c] = (short)h;
    ol[(size_t)row * D + c] = (short)f2bf(o - bf2f(h));
  }
}

// ---------------- final layernorm: f32 -> f32 ----------------
__global__ __launch_bounds__(256)
void layernorm_f32(const float* __restrict__ x, const float* __restrict__ w,
                   const float* __restrict__ bb, float* __restrict__ outf){
  int wave = threadIdx.x >> 6;
  int lane = threadIdx.x & 63;
  int row = blockIdx.x * 4 + wave;
  const float* xr = x + (size_t)row * D;
  float v[6];
  float s = 0.f, sq = 0.f;
  #pragma unroll
  for (int i = 0; i < 6; i++){ v[i] = xr[lane + 64 * i]; s += v[i]; sq += v[i] * v[i]; }
  #pragma unroll
  for (int off = 32; off; off >>= 1){ s += __shfl_xor(s, off); sq += __shfl_xor(sq, off); }
  float mean = s * (1.f / D);
  float var  = sq * (1.f / D) - mean * mean;
  float inv  = 1.0f / sqrtf(var + 1e-5f);
  #pragma unroll
  for (int i = 0; i < 6; i++){
    int c = lane + 64 * i;
    outf[(size_t)row * D + c] = (v[i] - mean) * inv * w[c] + bb[c];
  }
}

// ---------------- MFMA GEMM, pre-split bf16 hi/lo inputs (fp32-quality) ----------------
// C[M,N] = A * W^T + bias.  BM=64, BN=64, BK=32; 4 waves, each 64m x 16n.
// WSEL picks the device-global weight array; woff = per-layer offset.
// EPI: 0 = bias -> C[m*ncols+n]
//      1 = +pos -> C
//      2 = in-place residual add into C
//      4 = in-proj split: n<E -> C[m*E+n]; n>=E -> C2[(n-E)*M+m] = silu(v)
template<int WSEL, int EPI>
__global__ __launch_bounds__(256)
void gemm_bf(const short* __restrict__ Ah, const short* __restrict__ Al, int lda, int K,
             size_t woff, const float* __restrict__ bias,
             float* __restrict__ C, float* __restrict__ C2,
             const float* __restrict__ pos, int ncols){
  constexpr int BKp = 40;                      // 32 + 8 pad (2-way bank alias = free)
  __shared__ __align__(16) short sAh[64 * BKp], sAl[64 * BKp];
  __shared__ __align__(16) short sWh[64 * BKp], sWl[64 * BKp];
  const short* Wh = wsel_h<WSEL>() + woff;
  const short* Wl = wsel_l<WSEL>() + woff;
  const int t = threadIdx.x, wid = t >> 6, lane = t & 63;
  const int m0 = blockIdx.y * 64, n0 = blockIdx.x * 64;

  fx4 acc[4];
  #pragma unroll
  for (int a = 0; a < 4; a++)
    #pragma unroll
    for (int i = 0; i < 4; i++) acc[a][i] = 0.f;

  const int r = t >> 2, kp = (t & 3) << 3;     // 64 rows x 4 chunks of 8 shorts
  const int row = lane & 15, kq = lane >> 4;

  for (int kt = 0; kt < K; kt += 32){
    *(bf16x8*)&sAh[r * BKp + kp] = *(const bf16x8*)(Ah + (size_t)(m0 + r) * lda + kt + kp);
    *(bf16x8*)&sAl[r * BKp + kp] = *(const bf16x8*)(Al + (size_t)(m0 + r) * lda + kt + kp);
    *(bf16x8*)&sWh[r * BKp + kp] = *(const bf16x8*)(Wh + (size_t)(n0 + r) * K + kt + kp);
    *(bf16x8*)&sWl[r * BKp + kp] = *(const bf16x8*)(Wl + (size_t)(n0 + r) * K + kt + kp);
    __syncthreads();
    bf16x8 bh = *(const bf16x8*)&sWh[(wid * 16 + row) * BKp + kq * 8];
    bf16x8 bl = *(const bf16x8*)&sWl[(wid * 16 + row) * BKp + kq * 8];
    #pragma unroll
    for (int tm = 0; tm < 4; tm++){
      bf16x8 ah = *(const bf16x8*)&sAh[(tm * 16 + row) * BKp + kq * 8];
      bf16x8 al = *(const bf16x8*)&sAl[(tm * 16 + row) * BKp + kq * 8];
      acc[tm] = __builtin_amdgcn_mfma_f32_16x16x32_bf16(ah, bh, acc[tm], 0, 0, 0);
      acc[tm] = __builtin_amdgcn_mfma_f32_16x16x32_bf16(ah, bl, acc[tm], 0, 0, 0);
      acc[tm] = __builtin_amdgcn_mfma_f32_16x16x32_bf16(al, bh, acc[tm], 0, 0, 0);
    }
    __syncthreads();
  }

  const int row4 = (lane >> 4) * 4, coln = lane & 15;
  #pragma unroll
  for (int tm = 0; tm < 4; tm++)
    #pragma unroll
    for (int i = 0; i < 4; i++){
      int m = m0 + tm * 16 + row4 + i;
      int n = n0 + wid * 16 + coln;
      float v = acc[tm][i] + bias[n];
      if constexpr (EPI == 0){ C[(size_t)m * ncols + n] = v; }
      if constexpr (EPI == 1){ v += pos[(size_t)(m & (Np - 1)) * ncols + n];
                               C[(size_t)m * ncols + n] = v; }
      if constexpr (EPI == 2){ v += C[(size_t)m * ncols + n];
                               C[(size_t)m * ncols + n] = v; }
      if constexpr (EPI == 4){
        if (n < E) C[(size_t)m * E + n] = v;
        else {
          float sig = 1.f / (1.f + expf(-v));
          C2[(size_t)(n - E) * M + m] = v * sig;
        }
      }
    }
}

// ---------------- vector GEMM for dt (K=16): softplus+clip -> transposed C[n*M+m] ----------------
__global__ __launch_bounds__(256)
void gemm_dt(const float* __restrict__ A, const float* __restrict__ W,
             const float* __restrict__ bias, float* __restrict__ C){
  __shared__ float As[16][64 + 1];
  __shared__ float Ws[16][64 + 1];
  int tid = threadIdx.x;
  int tx = tid & 15, ty = tid >> 4;
  int m0 = blockIdx.y * 64, n0 = blockIdx.x * 64;
  float acc[4][4];
  #pragma unroll
  for (int i = 0; i < 4; i++)
    #pragma unroll
    for (int j = 0; j < 4; j++) acc[i][j] = 0.f;
  {
    int r = tid >> 2, kk = (tid & 3) << 2;
    const float* ap = A + (size_t)(m0 + r) * 32 + kk;
    As[kk + 0][r] = ap[0]; As[kk + 1][r] = ap[1];
    As[kk + 2][r] = ap[2]; As[kk + 3][r] = ap[3];
    const float* wp = W + (size_t)(n0 + r) * 16 + kk;
    Ws[kk + 0][r] = wp[0]; Ws[kk + 1][r] = wp[1];
    Ws[kk + 2][r] = wp[2]; Ws[kk + 3][r] = wp[3];
  }
  __syncthreads();
  #pragma unroll
  for (int k = 0; k < 16; k++){
    float a[4], w[4];
    #pragma unroll
    for (int i = 0; i < 4; i++) a[i] = As[k][ty * 4 + i];
    #pragma unroll
    for (int j = 0; j < 4; j++) w[j] = Ws[k][tx * 4 + j];
    #pragma unroll
    for (int i = 0; i < 4; i++)
      #pragma unroll
      for (int j = 0; j < 4; j++) acc[i][j] += a[i] * w[j];
  }
  #pragma unroll
  for (int i = 0; i < 4; i++){
    int m = m0 + ty * 4 + i;
    #pragma unroll
    for (int j = 0; j < 4; j++){
      int n = n0 + tx * 4 + j;
      float v = acc[i][j] + bias[n];
      v = (v > 15.f) ? v : log1pf(expf(v));
      v = fminf(fmaxf(v, 1e-4f), 1.0f);
      C[(size_t)n * M + m] = v;
    }
  }
}

// ---------------- xp GEMM: xBC[M,32] += xc[M,768] * xp_w[32,768]^T, K-split x4 ----------------
__global__ __launch_bounds__(256)
void gemm_xp(const float* __restrict__ A, const float* __restrict__ W,
             const float* __restrict__ bias, float* __restrict__ C){
  __shared__ float As[16][64 + 1];
  __shared__ float Ws[16][32 + 1];
  int tid = threadIdx.x;
  int tx = tid & 15, ty = tid >> 4;
  int m0 = blockIdx.y * 64, kb = blockIdx.x * 192;
  float acc[4][2];
  #pragma unroll
  for (int i = 0; i < 4; i++){ acc[i][0] = 0.f; acc[i][1] = 0.f; }
  for (int kt = kb; kt < kb + 192; kt += 16){
    {
      int r = tid >> 2, kk = (tid & 3) << 2;
      const float* ap = A + (size_t)(m0 + r) * E + kt + kk;
      As[kk + 0][r] = ap[0]; As[kk + 1][r] = ap[1];
      As[kk + 2][r] = ap[2]; As[kk + 3][r] = ap[3];
    }
    if (tid < 128){
      int c = tid >> 2, kk = (tid & 3) << 2;
      const float* wp = W + (size_t)c * E + kt + kk;
      Ws[kk + 0][c] = wp[0]; Ws[kk + 1][c] = wp[1];
      Ws[kk + 2][c] = wp[2]; Ws[kk + 3][c] = wp[3];
    }
    __syncthreads();
    #pragma unroll
    for (int k = 0; k < 16; k++){
      float a[4], w[2];
      #pragma unroll
      for (int i = 0; i < 4; i++) a[i] = As[k][ty * 4 + i];
      w[0] = Ws[k][tx * 2]; w[1] = Ws[k][tx * 2 + 1];
      #pragma unroll
      for (int i = 0; i < 4; i++){ acc[i][0] += a[i] * w[0]; acc[i][1] += a[i] * w[1]; }
    }
    __syncthreads();
  }
  #pragma unroll
  for (int i = 0; i < 4; i++){
    int m = m0 + ty * 4 + i;
    #pragma unroll
    for (int j = 0; j < 2; j++){
      int n = tx * 2 + j;
      float v = acc[i][j];
      if (blockIdx.x == 0) v += bias[n];
      atomicAdd(&C[(size_t)m * 32 + n], v);
    }
  }
}

// ---------------- depthwise causal conv (K=4) + SiLU, f32 ----------------
__global__ void conv_silu_kernel(const float* __restrict__ xm, const float* __restrict__ cw,
                                 const float* __restrict__ cb, float* __restrict__ xc){
  int idx = blockIdx.x * 256 + threadIdx.x;     // m*E + e
  if (idx >= M * E) return;
  int e = idx % E, m = idx / E;
  int n = m & (Np - 1);
  float acc = cb[e];
  #pragma unroll
  for (int kk = 0; kk < 4; kk++){
    int j = n - 3 + kk;
    if (j >= 0) acc += cw[e * 4 + kk] * xm[(size_t)(m - 3 + kk) * E + e];
  }
  float sig = 1.f / (1.f + expf(-acc));
  xc[idx] = acc * sig;
}

// ---------------- chunked selective scan; y emitted as hi/lo bf16 ----------------
__global__ __launch_bounds__(256)
void scan_kernel(const float* __restrict__ dtt, const float* __restrict__ xc,
                 const float* __restrict__ zst, const float* __restrict__ xBC,
                 const float* __restrict__ Aptr, const float* __restrict__ Dp,
                 short* __restrict__ yh, short* __restrict__ yl){
  __shared__ float yloc[1024];
  __shared__ float hloc[16][16], prodA[16][16], Hin[16][16];
  const int t = threadIdx.x, g = t >> 4, s = t & 15;
  const int r = blockIdx.x, b = r / E, e = r % E;
  const float a   = Aptr[e * S + s];
  const float dpe = Dp[e];
  const float* dtp = dtt + (size_t)e * M + b * Np;
  const float* zsp = zst + (size_t)e * M + b * Np;
  const int n0 = g * 64;
  const int mbase = b * Np + n0;

  float h = 0.f, P = 1.f;
  for (int i = 0; i < 64; i++){
    int n = n0 + i, m = mbase + i;
    float dt  = dtp[n];
    float xcv = xc[(size_t)m * E + e];
    float xb  = xBC[m * 32 + s];
    float xcs = xBC[m * 32 + 16 + s];
    float dA = __expf(fmaxf(dt * a, -20.f));
    h = dA * h + xb * xcv;
    P *= dA;
    float p = h * xcs;
    p += __shfl_xor(p, 8); p += __shfl_xor(p, 4);
    p += __shfl_xor(p, 2); p += __shfl_xor(p, 1);
    if (s == 0) yloc[n0 + i] = p + dpe * xcv;
  }
  hloc[g][s] = h; prodA[g][s] = P;
  __syncthreads();
  if (t < 16){
    float H = 0.f;
    #pragma unroll
    for (int g2 = 0; g2 < 16; g2++){
      Hin[g2][t] = H;
      H = prodA[g2][t] * H + hloc[g2][t];
    }
  }
  __syncthreads();
  float Q = Hin[g][s];
  for (int i = 0; i < 64; i++){
    int n = n0 + i, m = mbase + i;
    float dt  = dtp[n];
    float xcs = xBC[m * 32 + 16 + s];
    float dA = __expf(fmaxf(dt * a, -20.f));
    Q *= dA;
    float p = Q * xcs;
    p += __shfl_xor(p, 8); p += __shfl_xor(p, 4);
    p += __shfl_xor(p, 2); p += __shfl_xor(p, 1);
    if (s == 0){
      float val = (yloc[n0 + i] + p) * zsp[n];
      unsigned short hh = f2bf(val);
      size_t o = (size_t)m * E + e;
      yh[o] = (short)hh; yl[o] = (short)f2bf(val - bf2f(hh));
    }
  }
}

extern "C" void kernel_launch(void* const* d_in, const int* in_sizes, int n_in,
                              void* d_out, int out_size, void* d_ws, size_t ws_size,
                              hipStream_t stream){
  const float* px      = (const float*)d_in[0];
  const float* patch_w = (const float*)d_in[1];
  const float* patch_b = (const float*)d_in[2];
  const float* pos     = (const float*)d_in[3];
  const float* norm_w  = (const float*)d_in[4];
  const float* norm_b  = (const float*)d_in[5];
  const float* in_w    = (const float*)d_in[6];
  const float* in_b    = (const float*)d_in[7];
  const float* conv_w  = (const float*)d_in[8];
  const float* conv_b  = (const float*)d_in[9];
  const float* xp_w    = (const float*)d_in[10];
  const float* xp_b    = (const float*)d_in[11];
  const float* dt_w    = (const float*)d_in[12];
  const float* dt_b    = (const float*)d_in[13];
  const float* Aab     = (const float*)d_in[14];
  const float* Dp      = (const float*)d_in[15];
  const float* out_w   = (const float*)d_in[16];
  const float* out_b   = (const float*)d_in[17];
  const float* fnorm_w = (const float*)d_in[18];
  const float* fnorm_b = (const float*)d_in[19];
  const float* scale_w = (const float*)d_in[20];
  const float* scale_b = (const float*)d_in[21];
  float* out = (float*)d_out;

  // workspace (30.25 MB):
  // x f32 3MB | xzm f32 6MB (x_main; also hosts pbh/pbl and yh/yl as shorts)
  // zst 6MB | xc 6MB | xBC 0.25MB | dtt 6MB | xnh/xnl shorts 3MB
  float* x   = (float*)d_ws;                  // M*D
  float* xzm = x + (size_t)M * D;             // M*E f32
  float* zst = xzm + (size_t)M * E;           // M*E
  float* xc  = zst + (size_t)M * E;           // M*E
  float* xBC = xc + (size_t)M * E;            // M*32
  float* dtt = xBC + (size_t)M * 32;          // M*E
  short* xnh = (short*)(dtt + (size_t)M * E); // M*D
  short* xnl = xnh + (size_t)M * D;           // M*D
  short* yh  = (short*)xzm;                   // M*E shorts  (alias: dead x_main)
  short* yl  = yh + (size_t)M * E;            // M*E shorts  (exactly fills xzm's 6MB)
  short* pbh = yh, *pbl = yl;                 // patch buffer alias (dead before in-proj)

  constexpr size_t TOTW = PW_N + IW_N + OW_N + SW_N;
  convw_kernel<<<(int)((TOTW + 255) / 256), 256, 0, stream>>>(patch_w, in_w, out_w, scale_w);

  patchify_kernel<<<(M * 768 + 255) / 256, 256, 0, stream>>>(px, pbh, pbl);
  gemm_bf<0, 1><<<dim3(D / 64, M / 64), 256, 0, stream>>>(
      pbh, pbl, 768, 768, 0, patch_b, x, nullptr, pos, D);

  for (int l = 0; l < L; l++){
    layernorm_bf<<<M / 4, 256, 0, stream>>>(x, norm_w + l * D, norm_b + l * D, xnh, xnl);
    gemm_bf<1, 4><<<dim3(TWO_E / 64, M / 64), 256, 0, stream>>>(
        xnh, xnl, D, D, (size_t)l * TWO_E * D, in_b + l * TWO_E, xzm, zst, nullptr, TWO_E);
    conv_silu_kernel<<<(M * E + 255) / 256, 256, 0, stream>>>(
        xzm, conv_w + (size_t)l * E * 4, conv_b + l * E, xc);
    hipMemsetAsync(xBC, 0, (size_t)M * 32 * sizeof(float), stream);
    gemm_xp<<<dim3(4, M / 64), 256, 0, stream>>>(
        xc, xp_w + (size_t)l * 32 * E, xp_b + l * 32, xBC);
    gemm_dt<<<dim3(E / 64, M / 64), 256, 0, stream>>>(
        xBC, dt_w + (size_t)l * E * S, dt_b + l * E, dtt);
    scan_kernel<<<Bz * E, 256, 0, stream>>>(
        dtt, xc, zst, xBC, Aab + (size_t)l * E * S, Dp + l * E, yh, yl);
    gemm_bf<2, 2><<<dim3(D / 64, M / 64), 256, 0, stream>>>(
        yh, yl, E, E, (size_t)l * D * E, out_b + l * D, x, nullptr, nullptr, D);
    if (l % 4 == 0 && l / 4 < 3){
      int j = l / 4;
      convx_kernel<<<(M * D + 255) / 256, 256, 0, stream>>>(x, xnh, xnl);
      gemm_bf<3, 0><<<dim3(D / 64, M / 64), 256, 0, stream>>>(
          xnh, xnl, D, D, (size_t)j * D * D, scale_b + j * D,
          out + (size_t)(1 + j) * M * D, nullptr, nullptr, D);
    }
  }
  layernorm_f32<<<M / 4, 256, 0, stream>>>(x, fnorm_w, fnorm_b, out);
}

// Round 8
// 2129.972 us; speedup vs baseline: 5.7944x; 1.1047x over previous
//
#include <hip/hip_runtime.h>
#include <hip/hip_bf16.h>

// problem sizes
constexpr int Bz = 2, IMG = 512, Pp = 16, D = 384, E = 768, S = 16, L = 12;
constexpr int G = IMG / Pp;          // 32
constexpr int Np = G * G;            // 1024 patches
constexpr int M = Bz * Np;           // 2048 rows
constexpr int TWO_E = 2 * E;         // 1536

typedef short bf16x8 __attribute__((ext_vector_type(8)));
typedef float fx4    __attribute__((ext_vector_type(4)));

static __device__ __forceinline__ unsigned short f2bf(float f){
  unsigned int u = __float_as_uint(f);
  u = (u + 0x7FFFu + ((u >> 16) & 1u)) >> 16;       // RN-even
  return (unsigned short)u;
}
static __device__ __forceinline__ float bf2f(unsigned short h){
  return __uint_as_float(((unsigned int)h) << 16);
}

// ---------------- converted-weight store (device globals) ----------------
constexpr size_t PW_N = (size_t)D * 768;
constexpr size_t IW_N = (size_t)L * TWO_E * D;
constexpr size_t OW_N = (size_t)L * D * E;
constexpr size_t SW_N = (size_t)3 * D * D;
__device__ short g_pw_h[PW_N], g_pw_l[PW_N];
__device__ short g_iw_h[IW_N], g_iw_l[IW_N];
__device__ short g_ow_h[OW_N], g_ow_l[OW_N];
__device__ short g_sw_h[SW_N], g_sw_l[SW_N];

template<int WSEL> __device__ __forceinline__ const short* wsel_h(){
  if constexpr (WSEL == 0) return g_pw_h;
  else if constexpr (WSEL == 1) return g_iw_h;
  else if constexpr (WSEL == 2) return g_ow_h;
  else return g_sw_h;
}
template<int WSEL> __device__ __forceinline__ const short* wsel_l(){
  if constexpr (WSEL == 0) return g_pw_l;
  else if constexpr (WSEL == 1) return g_iw_l;
  else if constexpr (WSEL == 2) return g_ow_l;
  else return g_sw_l;
}

__global__ void convw_kernel(const float* __restrict__ pw, const float* __restrict__ iw,
                             const float* __restrict__ ow, const float* __restrict__ sw){
  size_t i = (size_t)blockIdx.x * 256 + threadIdx.x;
  if (i >= PW_N + IW_N + OW_N + SW_N) return;
  const float* src; short *dh, *dl; size_t j = i;
  if (j < PW_N){ src = pw; dh = g_pw_h; dl = g_pw_l; }
  else if ((j -= PW_N) < IW_N){ src = iw; dh = g_iw_h; dl = g_iw_l; }
  else if ((j -= IW_N) < OW_N){ src = ow; dh = g_ow_h; dl = g_ow_l; }
  else { j -= OW_N; src = sw; dh = g_sw_h; dl = g_sw_l; }
  float f = src[j];
  unsigned short h = f2bf(f);
  dh[j] = (short)h; dl[j] = (short)f2bf(f - bf2f(h));
}

// ---------------- patchify: pixels(f32) -> hi/lo bf16 (M x 768) ----------------
__global__ void patchify_kernel(const float* __restrict__ px,
                                short* __restrict__ oh, short* __restrict__ ol){
  int idx = blockIdx.x * 256 + threadIdx.x;
  if (idx >= M * 768) return;
  int k = idx % 768, m = idx / 768;
  int b = m / Np, n = m % Np;
  int gy = n / G, gx = n % G;
  int c = k / (Pp * Pp), r = k % (Pp * Pp);
  int py = r / Pp, pxi = r % Pp;
  size_t src = ((size_t)(b * 3 + c) * IMG + gy * Pp + py) * IMG + gx * Pp + pxi;
  float f = px[src];
  unsigned short h = f2bf(f);
  oh[idx] = (short)h; ol[idx] = (short)f2bf(f - bf2f(h));
}

// ---------------- convert f32 -> hi/lo bf16 ----------------
__global__ void convx_kernel(const float* __restrict__ x,
                             short* __restrict__ oh, short* __restrict__ ol){
  int idx = blockIdx.x * 256 + threadIdx.x;
  if (idx >= M * D) return;
  float f = x[idx];
  unsigned short h = f2bf(f);
  oh[idx] = (short)h; ol[idx] = (short)f2bf(f - bf2f(h));
}

// ---------------- layernorm D=384: f32 in -> hi/lo bf16 out ----------------
__global__ __launch_bounds__(256)
void layernorm_bf(const float* __restrict__ x, const float* __restrict__ w,
                  const float* __restrict__ bb, short* __restrict__ oh,
                  short* __restrict__ ol){
  int wave = threadIdx.x >> 6, lane = threadIdx.x & 63;
  int row = blockIdx.x * 4 + wave;
  const float* xr = x + (size_t)row * D;
  float v[6], s = 0.f, sq = 0.f;
  #pragma unroll
  for (int i = 0; i < 6; i++){ v[i] = xr[lane + 64 * i]; s += v[i]; sq += v[i] * v[i]; }
  #pragma unroll
  for (int off = 32; off; off >>= 1){ s += __shfl_xor(s, off); sq += __shfl_xor(sq, off); }
  float mean = s * (1.f / D);
  float var  = sq * (1.f / D) - mean * mean;
  float inv  = 1.0f / sqrtf(var + 1e-5f);
  #pragma unroll
  for (int i = 0; i < 6; i++){
    int c = lane + 64 * i;
    float o = (v[i] - mean) * inv * w[c] + bb[c];
    unsigned short h = f2bf(o);
    oh[(size_t)row * D + c] = (short)h;
    ol[(size_t)row * D + c] = (short)f2bf(o - bf2f(h));
  }
}

// ---------------- final layernorm: f32 -> f32 ----------------
__global__ __launch_bounds__(256)
void layernorm_f32(const float* __restrict__ x, const float* __restrict__ w,
                   const float* __restrict__ bb, float* __restrict__ outf){
  int wave = threadIdx.x >> 6, lane = threadIdx.x & 63;
  int row = blockIdx.x * 4 + wave;
  const float* xr = x + (size_t)row * D;
  float v[6], s = 0.f, sq = 0.f;
  #pragma unroll
  for (int i = 0; i < 6; i++){ v[i] = xr[lane + 64 * i]; s += v[i]; sq += v[i] * v[i]; }
  #pragma unroll
  for (int off = 32; off; off >>= 1){ s += __shfl_xor(s, off); sq += __shfl_xor(sq, off); }
  float mean = s * (1.f / D);
  float var  = sq * (1.f / D) - mean * mean;
  float inv  = 1.0f / sqrtf(var + 1e-5f);
  #pragma unroll
  for (int i = 0; i < 6; i++){
    int c = lane + 64 * i;
    outf[(size_t)row * D + c] = (v[i] - mean) * inv * w[c] + bb[c];
  }
}

// ---------------- MFMA GEMM, row-major A (pre-split hi/lo) ----------------
// EPI: 0 = bias -> C[m*ncols+n]; 1 = +pos -> C; 2 = residual add in-place;
//      4 = in-proj split: n<E -> xmT[n*M+m] (f32, transposed); n>=E -> C2[(n-E)*M+m]=silu
template<int WSEL, int EPI>
__global__ __launch_bounds__(256)
void gemm_bf(const short* __restrict__ Ah, const short* __restrict__ Al, int lda, int K,
             size_t woff, const float* __restrict__ bias,
             float* __restrict__ C, float* __restrict__ C2,
             const float* __restrict__ pos, int ncols){
  constexpr int BKp = 40;
  __shared__ __align__(16) short sAh[64 * BKp], sAl[64 * BKp];
  __shared__ __align__(16) short sWh[64 * BKp], sWl[64 * BKp];
  const short* Wh = wsel_h<WSEL>() + woff;
  const short* Wl = wsel_l<WSEL>() + woff;
  const int t = threadIdx.x, wid = t >> 6, lane = t & 63;
  const int m0 = blockIdx.y * 64, n0 = blockIdx.x * 64;

  fx4 acc[4];
  #pragma unroll
  for (int a = 0; a < 4; a++)
    #pragma unroll
    for (int i = 0; i < 4; i++) acc[a][i] = 0.f;

  const int r = t >> 2, kp = (t & 3) << 3;
  const int row = lane & 15, kq = lane >> 4;

  for (int kt = 0; kt < K; kt += 32){
    *(bf16x8*)&sAh[r * BKp + kp] = *(const bf16x8*)(Ah + (size_t)(m0 + r) * lda + kt + kp);
    *(bf16x8*)&sAl[r * BKp + kp] = *(const bf16x8*)(Al + (size_t)(m0 + r) * lda + kt + kp);
    *(bf16x8*)&sWh[r * BKp + kp] = *(const bf16x8*)(Wh + (size_t)(n0 + r) * K + kt + kp);
    *(bf16x8*)&sWl[r * BKp + kp] = *(const bf16x8*)(Wl + (size_t)(n0 + r) * K + kt + kp);
    __syncthreads();
    bf16x8 bh = *(const bf16x8*)&sWh[(wid * 16 + row) * BKp + kq * 8];
    bf16x8 bl = *(const bf16x8*)&sWl[(wid * 16 + row) * BKp + kq * 8];
    #pragma unroll
    for (int tm = 0; tm < 4; tm++){
      bf16x8 ah = *(const bf16x8*)&sAh[(tm * 16 + row) * BKp + kq * 8];
      bf16x8 al = *(const bf16x8*)&sAl[(tm * 16 + row) * BKp + kq * 8];
      acc[tm] = __builtin_amdgcn_mfma_f32_16x16x32_bf16(ah, bh, acc[tm], 0, 0, 0);
      acc[tm] = __builtin_amdgcn_mfma_f32_16x16x32_bf16(ah, bl, acc[tm], 0, 0, 0);
      acc[tm] = __builtin_amdgcn_mfma_f32_16x16x32_bf16(al, bh, acc[tm], 0, 0, 0);
    }
    __syncthreads();
  }

  const int row4 = (lane >> 4) * 4, coln = lane & 15;
  #pragma unroll
  for (int tm = 0; tm < 4; tm++){
    int n = n0 + wid * 16 + coln;
    int mb = m0 + tm * 16 + row4;
    if constexpr (EPI == 4){
      float4 v4;
      float* vp = (float*)&v4;
      #pragma unroll
      for (int i = 0; i < 4; i++) vp[i] = acc[tm][i] + bias[n];
      if (n < E){
        *(float4*)&C[(size_t)n * M + mb] = v4;          // xmT transposed
      } else {
        #pragma unroll
        for (int i = 0; i < 4; i++){
          float sig = 1.f / (1.f + expf(-vp[i]));
          vp[i] = vp[i] * sig;
        }
        *(float4*)&C2[(size_t)(n - E) * M + mb] = v4;   // zst transposed
      }
    } else {
      #pragma unroll
      for (int i = 0; i < 4; i++){
        int m = mb + i;
        float v = acc[tm][i] + bias[n];
        if constexpr (EPI == 1) v += pos[(size_t)(m & (Np - 1)) * ncols + n];
        if constexpr (EPI == 2) v += C[(size_t)m * ncols + n];
        C[(size_t)m * ncols + n] = v;
      }
    }
  }
}

// ---------------- MFMA GEMM, TRANSPOSED A ([K][M] hi/lo shorts), EPI=residual add ----------------
__global__ __launch_bounds__(256)
void gemm_bf_at(const short* __restrict__ ATh, const short* __restrict__ ATl, int K,
                size_t woff, const float* __restrict__ bias,
                float* __restrict__ C, int ncols){
  constexpr int BKp = 40;
  __shared__ __align__(16) short sAh[64 * BKp], sAl[64 * BKp];
  __shared__ __align__(16) short sWh[64 * BKp], sWl[64 * BKp];
  const short* Wh = g_ow_h + woff;
  const short* Wl = g_ow_l + woff;
  const int t = threadIdx.x, wid = t >> 6, lane = t & 63;
  const int m0 = blockIdx.y * 64, n0 = blockIdx.x * 64;

  fx4 acc[4];
  #pragma unroll
  for (int a = 0; a < 4; a++)
    #pragma unroll
    for (int i = 0; i < 4; i++) acc[a][i] = 0.f;

  const int rw = t >> 2, kpw = (t & 3) << 3;        // W staging (row-major)
  const int kr2 = (t & 15) * 2, mc4 = (t >> 4) * 4; // A staging (transposed)
  const int row = lane & 15, kq = lane >> 4;

  for (int kt = 0; kt < K; kt += 32){
    { // A: rows kr2,kr2+1 of AT, 4 m each; pack pairs -> b32 LDS writes
      const uint2 h0 = *(const uint2*)(ATh + (size_t)(kt + kr2) * M + m0 + mc4);
      const uint2 h1 = *(const uint2*)(ATh + (size_t)(kt + kr2 + 1) * M + m0 + mc4);
      const uint2 l0 = *(const uint2*)(ATl + (size_t)(kt + kr2) * M + m0 + mc4);
      const uint2 l1 = *(const uint2*)(ATl + (size_t)(kt + kr2 + 1) * M + m0 + mc4);
      const unsigned int h0a[2] = {h0.x, h0.y}, h1a[2] = {h1.x, h1.y};
      const unsigned int l0a[2] = {l0.x, l0.y}, l1a[2] = {l1.x, l1.y};
      #pragma unroll
      for (int j = 0; j < 4; j++){
        unsigned int s0 = (h0a[j >> 1] >> ((j & 1) * 16)) & 0xFFFFu;
        unsigned int s1 = (h1a[j >> 1] >> ((j & 1) * 16)) & 0xFFFFu;
        *(unsigned int*)&sAh[(mc4 + j) * BKp + kr2] = s0 | (s1 << 16);
        unsigned int t0 = (l0a[j >> 1] >> ((j & 1) * 16)) & 0xFFFFu;
        unsigned int t1 = (l1a[j >> 1] >> ((j & 1) * 16)) & 0xFFFFu;
        *(unsigned int*)&sAl[(mc4 + j) * BKp + kr2] = t0 | (t1 << 16);
      }
    }
    *(bf16x8*)&sWh[rw * BKp + kpw] = *(const bf16x8*)(Wh + (size_t)(n0 + rw) * K + kt + kpw);
    *(bf16x8*)&sWl[rw * BKp + kpw] = *(const bf16x8*)(Wl + (size_t)(n0 + rw) * K + kt + kpw);
    __syncthreads();
    bf16x8 bh = *(const bf16x8*)&sWh[(wid * 16 + row) * BKp + kq * 8];
    bf16x8 bl = *(const bf16x8*)&sWl[(wid * 16 + row) * BKp + kq * 8];
    #pragma unroll
    for (int tm = 0; tm < 4; tm++){
      bf16x8 ah = *(const bf16x8*)&sAh[(tm * 16 + row) * BKp + kq * 8];
      bf16x8 al = *(const bf16x8*)&sAl[(tm * 16 + row) * BKp + kq * 8];
      acc[tm] = __builtin_amdgcn_mfma_f32_16x16x32_bf16(ah, bh, acc[tm], 0, 0, 0);
      acc[tm] = __builtin_amdgcn_mfma_f32_16x16x32_bf16(ah, bl, acc[tm], 0, 0, 0);
      acc[tm] = __builtin_amdgcn_mfma_f32_16x16x32_bf16(al, bh, acc[tm], 0, 0, 0);
    }
    __syncthreads();
  }

  const int row4 = (lane >> 4) * 4, coln = lane & 15;
  #pragma unroll
  for (int tm = 0; tm < 4; tm++)
    #pragma unroll
    for (int i = 0; i < 4; i++){
      int m = m0 + tm * 16 + row4 + i;
      int n = n0 + wid * 16 + coln;
      float v = acc[tm][i] + bias[n] + C[(size_t)m * ncols + n];
      C[(size_t)m * ncols + n] = v;
    }
}

// ---------------- xp GEMM (K-split, partial outputs): xBC4[p][M][32] ----------------
__global__ __launch_bounds__(256)
void gemm_xp(const float* __restrict__ xcT, const float* __restrict__ W,
             const float* __restrict__ bias, float* __restrict__ C4){
  __shared__ float As[16][64 + 1];
  __shared__ float Ws[16][32 + 1];
  int tid = threadIdx.x;
  int tx = tid & 15, ty = tid >> 4;
  int m0 = blockIdx.y * 64, kb = blockIdx.x * 192;
  float acc[4][2];
  #pragma unroll
  for (int i = 0; i < 4; i++){ acc[i][0] = 0.f; acc[i][1] = 0.f; }
  for (int kt = kb; kt < kb + 192; kt += 16){
    #pragma unroll
    for (int ps = 0; ps < 4; ps++){
      int rr = (tid >> 6) + 4 * ps, mc = tid & 63;
      As[rr][mc] = xcT[(size_t)(kt + rr) * M + m0 + mc];
    }
    if (tid < 128){
      int c = tid >> 2, kk = (tid & 3) << 2;
      const float* wp = W + (size_t)c * E + kt + kk;
      Ws[kk + 0][c] = wp[0]; Ws[kk + 1][c] = wp[1];
      Ws[kk + 2][c] = wp[2]; Ws[kk + 3][c] = wp[3];
    }
    __syncthreads();
    #pragma unroll
    for (int k = 0; k < 16; k++){
      float a[4], w[2];
      #pragma unroll
      for (int i = 0; i < 4; i++) a[i] = As[k][ty * 4 + i];
      w[0] = Ws[k][tx * 2]; w[1] = Ws[k][tx * 2 + 1];
      #pragma unroll
      for (int i = 0; i < 4; i++){ acc[i][0] += a[i] * w[0]; acc[i][1] += a[i] * w[1]; }
    }
    __syncthreads();
  }
  float* Cp = C4 + (size_t)blockIdx.x * M * 32;
  #pragma unroll
  for (int i = 0; i < 4; i++){
    int m = m0 + ty * 4 + i;
    #pragma unroll
    for (int j = 0; j < 2; j++){
      int n = tx * 2 + j;
      float v = acc[i][j];
      if (blockIdx.x == 0) v += bias[n];
      Cp[(size_t)m * 32 + n] = v;
    }
  }
}

// ---------------- dt GEMM: sums xBC4 partials, writes dt^T and fused xBC ----------------
__global__ __launch_bounds__(256)
void gemm_dt(const float* __restrict__ C4, const float* __restrict__ W,
             const float* __restrict__ bias, float* __restrict__ dtt,
             float* __restrict__ xBC){
  __shared__ float As[32][64 + 1];
  __shared__ float Ws[16][64 + 1];
  int tid = threadIdx.x;
  int tx = tid & 15, ty = tid >> 4;
  int m0 = blockIdx.y * 64, n0 = blockIdx.x * 64;
  { // stage A: sum 4 partials; thread: m = tid&63, k8 = (tid>>6)*8
    int mm = tid & 63, k8 = (tid >> 6) * 8;
    float s[8];
    #pragma unroll
    for (int j = 0; j < 8; j++) s[j] = 0.f;
    #pragma unroll
    for (int p = 0; p < 4; p++){
      const float* src = C4 + (size_t)p * M * 32 + (size_t)(m0 + mm) * 32 + k8;
      float4 a = *(const float4*)src, b = *(const float4*)(src + 4);
      s[0] += a.x; s[1] += a.y; s[2] += a.z; s[3] += a.w;
      s[4] += b.x; s[5] += b.y; s[6] += b.z; s[7] += b.w;
    }
    #pragma unroll
    for (int j = 0; j < 8; j++) As[k8 + j][mm] = s[j];
    if (blockIdx.x == 0){
      float* dst = xBC + (size_t)(m0 + mm) * 32 + k8;
      *(float4*)dst = make_float4(s[0], s[1], s[2], s[3]);
      *(float4*)(dst + 4) = make_float4(s[4], s[5], s[6], s[7]);
    }
  }
  { // stage W (K=16)
    int rr = tid >> 2, kk = (tid & 3) << 2;
    const float* wp = W + (size_t)(n0 + rr) * 16 + kk;
    Ws[kk + 0][rr] = wp[0]; Ws[kk + 1][rr] = wp[1];
    Ws[kk + 2][rr] = wp[2]; Ws[kk + 3][rr] = wp[3];
  }
  __syncthreads();
  float acc[4][4];
  #pragma unroll
  for (int i = 0; i < 4; i++)
    #pragma unroll
    for (int j = 0; j < 4; j++) acc[i][j] = 0.f;
  #pragma unroll
  for (int k = 0; k < 16; k++){
    float a[4], w[4];
    #pragma unroll
    for (int i = 0; i < 4; i++) a[i] = As[k][ty * 4 + i];
    #pragma unroll
    for (int j = 0; j < 4; j++) w[j] = Ws[k][tx * 4 + j];
    #pragma unroll
    for (int i = 0; i < 4; i++)
      #pragma unroll
      for (int j = 0; j < 4; j++) acc[i][j] += a[i] * w[j];
  }
  #pragma unroll
  for (int i = 0; i < 4; i++){
    int m = m0 + ty * 4 + i;
    #pragma unroll
    for (int j = 0; j < 4; j++){
      int n = n0 + tx * 4 + j;
      float v = acc[i][j] + bias[n];
      v = (v > 15.f) ? v : log1pf(expf(v));
      v = fminf(fmaxf(v, 1e-4f), 1.0f);
      dtt[(size_t)n * M + m] = v;
    }
  }
}

// ---------------- depthwise causal conv (K=4) + SiLU on transposed layout ----------------
__global__ __launch_bounds__(256)
void conv_silu_t(const float* __restrict__ xmT, const float* __restrict__ cw,
                 const float* __restrict__ cb, float* __restrict__ xcT){
  const int e = blockIdx.x, t = threadIdx.x;
  const float w0 = cw[e * 4], w1 = cw[e * 4 + 1], w2 = cw[e * 4 + 2], w3 = cw[e * 4 + 3];
  const float bias = cb[e];
  const float* src = xmT + (size_t)e * M;
  float* dst = xcT + (size_t)e * M;
  int mb = t * 8;
  #pragma unroll
  for (int j = 0; j < 8; j++){
    int m = mb + j, n = m & (Np - 1);
    float acc = bias + w3 * src[m];
    if (n >= 1) acc += w2 * src[m - 1];
    if (n >= 2) acc += w1 * src[m - 2];
    if (n >= 3) acc += w0 * src[m - 3];
    float sig = 1.f / (1.f + expf(-acc));
    dst[m] = acc * sig;
  }
}

// ---------------- chunked selective scan (transposed IO, coalesced bf16 y) ----------------
__global__ __launch_bounds__(256)
void scan_kernel(const float* __restrict__ dtt, const float* __restrict__ xcT,
                 const float* __restrict__ zst, const float* __restrict__ xBC,
                 const float* __restrict__ Aptr, const float* __restrict__ Dp,
                 short* __restrict__ yh, short* __restrict__ yl){
  __shared__ float yloc[16 * 65];
  __shared__ float sdt[64 * 17], sxc[64 * 17];
  __shared__ float hloc[16][16], prodA[16][16], Hin[16][16];
  const int t = threadIdx.x, g = t >> 4, s = t & 15;
  const int r = blockIdx.x, b = r / E, e = r % E;
  const float a   = Aptr[e * S + s];
  const float dpe = Dp[e];
  const float* dtp = dtt + (size_t)e * M + b * Np;
  const float* xcp = xcT + (size_t)e * M + b * Np;
  const float* zsp = zst + (size_t)e * M + b * Np;

  // preload dt, xc rows into LDS (17-stride transposed: conflict-free R/W)
  #pragma unroll
  for (int q = t; q < 1024; q += 256){
    sdt[(q & 63) * 17 + (q >> 6)] = dtp[q];
    sxc[(q & 63) * 17 + (q >> 6)] = xcp[q];
  }
  __syncthreads();

  const int n0 = g * 64;
  const int mbase = b * Np + n0;

  float h = 0.f, P = 1.f;
  #pragma unroll 8
  for (int i = 0; i < 64; i++){
    int m = mbase + i;
    float dt  = sdt[i * 17 + g];
    float xcv = sxc[i * 17 + g];
    float xb  = xBC[m * 32 + s];
    float xcs = xBC[m * 32 + 16 + s];
    float dA = __expf(fmaxf(dt * a, -20.f));
    h = dA * h + xb * xcv;
    P *= dA;
    float p = h * xcs;
    p += __shfl_xor(p, 8); p += __shfl_xor(p, 4);
    p += __shfl_xor(p, 2); p += __shfl_xor(p, 1);
    if (s == 0) yloc[g * 65 + i] = p + dpe * xcv;
  }
  hloc[g][s] = h; prodA[g][s] = P;
  __syncthreads();
  if (t < 16){
    float H = 0.f;
    #pragma unroll
    for (int g2 = 0; g2 < 16; g2++){
      Hin[g2][t] = H;
      H = prodA[g2][t] * H + hloc[g2][t];
    }
  }
  __syncthreads();
  float Q = Hin[g][s];
  #pragma unroll 8
  for (int i = 0; i < 64; i++){
    int m = mbase + i;
    float dt  = sdt[i * 17 + g];
    float xcs = xBC[m * 32 + 16 + s];
    float dA = __expf(fmaxf(dt * a, -20.f));
    Q *= dA;
    float p = Q * xcs;
    p += __shfl_xor(p, 8); p += __shfl_xor(p, 4);
    p += __shfl_xor(p, 2); p += __shfl_xor(p, 1);
    if (s == 0) yloc[g * 65 + i] += p;
  }
  __syncthreads();
  { // coalesced hi/lo bf16 write, [e][m] layout
    int n4 = t * 4;
    float4 z4 = *(const float4*)&zsp[n4];
    const float* zp = (const float*)&z4;
    int gy = n4 >> 6, iy = n4 & 63;
    unsigned int hpack[2], lpack[2];
    #pragma unroll
    for (int half = 0; half < 2; half++){
      unsigned int hp = 0, lp = 0;
      #pragma unroll
      for (int j = 0; j < 2; j++){
        float val = yloc[gy * 65 + iy + half * 2 + j] * zp[half * 2 + j];
        unsigned short hh = f2bf(val);
        unsigned short ll = f2bf(val - bf2f(hh));
        hp |= ((unsigned int)hh) << (16 * j);
        lp |= ((unsigned int)ll) << (16 * j);
      }
      hpack[half] = hp; lpack[half] = lp;
    }
    size_t o = (size_t)e * M + b * Np + n4;
    *(uint2*)&yh[o] = make_uint2(hpack[0], hpack[1]);
    *(uint2*)&yl[o] = make_uint2(lpack[0], lpack[1]);
  }
}

extern "C" void kernel_launch(void* const* d_in, const int* in_sizes, int n_in,
                              void* d_out, int out_size, void* d_ws, size_t ws_size,
                              hipStream_t stream){
  const float* px      = (const float*)d_in[0];
  const float* patch_w = (const float*)d_in[1];
  const float* patch_b = (const float*)d_in[2];
  const float* pos     = (const float*)d_in[3];
  const float* norm_w  = (const float*)d_in[4];
  const float* norm_b  = (const float*)d_in[5];
  const float* in_w    = (const float*)d_in[6];
  const float* in_b    = (const float*)d_in[7];
  const float* conv_w  = (const float*)d_in[8];
  const float* conv_b  = (const float*)d_in[9];
  const float* xp_w    = (const float*)d_in[10];
  const float* xp_b    = (const float*)d_in[11];
  const float* dt_w    = (const float*)d_in[12];
  const float* dt_b    = (const float*)d_in[13];
  const float* Aab     = (const float*)d_in[14];
  const float* Dp      = (const float*)d_in[15];
  const float* out_w   = (const float*)d_in[16];
  const float* out_b   = (const float*)d_in[17];
  const float* fnorm_w = (const float*)d_in[18];
  const float* fnorm_b = (const float*)d_in[19];
  const float* scale_w = (const float*)d_in[20];
  const float* scale_b = (const float*)d_in[21];
  float* out = (float*)d_out;

  // workspace (30.25 MB):
  // x f32 3MB | xmT f32 6MB (hosts pbh/pbl and yh/yl shorts) | zst 6MB | xcT 6MB
  // xBC 0.25MB | dtt 6MB | xnh/xnl shorts 3MB (hosts xBC4 1MB)
  float* x   = (float*)d_ws;                  // M*D
  float* xmT = x + (size_t)M * D;             // E*M f32 (transposed x_main)
  float* zst = xmT + (size_t)M * E;           // E*M
  float* xcT = zst + (size_t)M * E;           // E*M
  float* xBC = xcT + (size_t)M * E;           // M*32
  float* dtt = xBC + (size_t)M * 32;          // E*M
  short* xnh = (short*)(dtt + (size_t)M * E); // M*D
  short* xnl = xnh + (size_t)M * D;           // M*D
  float* xBC4 = (float*)xnh;                  // 4*M*32 (alias: dead vs xnh timing)
  short* yh  = (short*)xmT;                   // E*M shorts (alias: dead x_main)
  short* yl  = yh + (size_t)M * E;
  short* pbh = yh, *pbl = yl;                 // patch buffer alias

  constexpr size_t TOTW = PW_N + IW_N + OW_N + SW_N;
  convw_kernel<<<(int)((TOTW + 255) / 256), 256, 0, stream>>>(patch_w, in_w, out_w, scale_w);

  patchify_kernel<<<(M * 768 + 255) / 256, 256, 0, stream>>>(px, pbh, pbl);
  gemm_bf<0, 1><<<dim3(D / 64, M / 64), 256, 0, stream>>>(
      pbh, pbl, 768, 768, 0, patch_b, x, nullptr, pos, D);

  for (int l = 0; l < L; l++){
    layernorm_bf<<<M / 4, 256, 0, stream>>>(x, norm_w + l * D, norm_b + l * D, xnh, xnl);
    gemm_bf<1, 4><<<dim3(TWO_E / 64, M / 64), 256, 0, stream>>>(
        xnh, xnl, D, D, (size_t)l * TWO_E * D, in_b + l * TWO_E, xmT, zst, nullptr, TWO_E);
    conv_silu_t<<<E, 256, 0, stream>>>(
        xmT, conv_w + (size_t)l * E * 4, conv_b + l * E, xcT);
    gemm_xp<<<dim3(4, M / 64), 256, 0, stream>>>(
        xcT, xp_w + (size_t)l * 32 * E, xp_b + l * 32, xBC4);
    gemm_dt<<<dim3(E / 64, M / 64), 256, 0, stream>>>(
        xBC4, dt_w + (size_t)l * E * S, dt_b + l * E, dtt, xBC);
    scan_kernel<<<Bz * E, 256, 0, stream>>>(
        dtt, xcT, zst, xBC, Aab + (size_t)l * E * S, Dp + l * E, yh, yl);
    gemm_bf_at<<<dim3(D / 64, M / 64), 256, 0, stream>>>(
        yh, yl, E, (size_t)l * D * E, out_b + l * D, x, D);
    if (l % 4 == 0 && l / 4 < 3){
      int j = l / 4;
      convx_kernel<<<(M * D + 255) / 256, 256, 0, stream>>>(x, xnh, xnl);
      gemm_bf<3, 0><<<dim3(D / 64, M / 64), 256, 0, stream>>>(
          xnh, xnl, D, D, (size_t)j * D * D, scale_b + j * D,
          out + (size_t)(1 + j) * M * D, nullptr, nullptr, D);
    }
  }
  layernorm_f32<<<M / 4, 256, 0, stream>>>(x, fnorm_w, fnorm_b, out);
}

// Round 9
// 1883.033 us; speedup vs baseline: 6.5543x; 1.1311x over previous
//
#include <hip/hip_runtime.h>
#include <hip/hip_bf16.h>

// problem sizes
constexpr int Bz = 2, IMG = 512, Pp = 16, D = 384, E = 768, S = 16, L = 12;
constexpr int G = IMG / Pp;          // 32
constexpr int Np = G * G;            // 1024 patches
constexpr int M = Bz * Np;           // 2048 rows
constexpr int TWO_E = 2 * E;         // 1536

typedef short bf16x8 __attribute__((ext_vector_type(8)));
typedef float fx4    __attribute__((ext_vector_type(4)));

static __device__ __forceinline__ unsigned short f2bf(float f){
  unsigned int u = __float_as_uint(f);
  u = (u + 0x7FFFu + ((u >> 16) & 1u)) >> 16;       // RN-even
  return (unsigned short)u;
}
static __device__ __forceinline__ float bf2f(unsigned short h){
  return __uint_as_float(((unsigned int)h) << 16);
}

// DPP row-rotate add: sums 16-lane rows without LDS (row_ror:N, full-rate VALU)
template<int N>
static __device__ __forceinline__ float ror_add(float v){
  int x = __builtin_amdgcn_update_dpp(0, __float_as_int(v), 0x120 | N, 0xF, 0xF, true);
  return v + __int_as_float(x);
}
static __device__ __forceinline__ float row_sum16(float v){
  v = ror_add<8>(v); v = ror_add<4>(v); v = ror_add<2>(v); v = ror_add<1>(v);
  return v;   // every lane of the 16-row holds the sum
}

// ---------------- converted-weight store (device globals) ----------------
constexpr size_t PW_N = (size_t)D * 768;
constexpr size_t IW_N = (size_t)L * TWO_E * D;
constexpr size_t OW_N = (size_t)L * D * E;
constexpr size_t SW_N = (size_t)3 * D * D;
__device__ short g_pw_h[PW_N], g_pw_l[PW_N];
__device__ short g_iw_h[IW_N], g_iw_l[IW_N];
__device__ short g_ow_h[OW_N], g_ow_l[OW_N];
__device__ short g_sw_h[SW_N], g_sw_l[SW_N];

template<int WSEL> __device__ __forceinline__ const short* wsel_h(){
  if constexpr (WSEL == 0) return g_pw_h;
  else if constexpr (WSEL == 1) return g_iw_h;
  else if constexpr (WSEL == 2) return g_ow_h;
  else return g_sw_h;
}
template<int WSEL> __device__ __forceinline__ const short* wsel_l(){
  if constexpr (WSEL == 0) return g_pw_l;
  else if constexpr (WSEL == 1) return g_iw_l;
  else if constexpr (WSEL == 2) return g_ow_l;
  else return g_sw_l;
}

__global__ void convw_kernel(const float* __restrict__ pw, const float* __restrict__ iw,
                             const float* __restrict__ ow, const float* __restrict__ sw){
  size_t i = (size_t)blockIdx.x * 256 + threadIdx.x;
  if (i >= PW_N + IW_N + OW_N + SW_N) return;
  const float* src; short *dh, *dl; size_t j = i;
  if (j < PW_N){ src = pw; dh = g_pw_h; dl = g_pw_l; }
  else if ((j -= PW_N) < IW_N){ src = iw; dh = g_iw_h; dl = g_iw_l; }
  else if ((j -= IW_N) < OW_N){ src = ow; dh = g_ow_h; dl = g_ow_l; }
  else { j -= OW_N; src = sw; dh = g_sw_h; dl = g_sw_l; }
  float f = src[j];
  unsigned short h = f2bf(f);
  dh[j] = (short)h; dl[j] = (short)f2bf(f - bf2f(h));
}

// ---------------- patchify: pixels(f32) -> hi/lo bf16 (M x 768) ----------------
__global__ void patchify_kernel(const float* __restrict__ px,
                                short* __restrict__ oh, short* __restrict__ ol){
  int idx = blockIdx.x * 256 + threadIdx.x;
  if (idx >= M * 768) return;
  int k = idx % 768, m = idx / 768;
  int b = m / Np, n = m % Np;
  int gy = n / G, gx = n % G;
  int c = k / (Pp * Pp), r = k % (Pp * Pp);
  int py = r / Pp, pxi = r % Pp;
  size_t src = ((size_t)(b * 3 + c) * IMG + gy * Pp + py) * IMG + gx * Pp + pxi;
  float f = px[src];
  unsigned short h = f2bf(f);
  oh[idx] = (short)h; ol[idx] = (short)f2bf(f - bf2f(h));
}

// ---------------- convert f32 -> hi/lo bf16 ----------------
__global__ void convx_kernel(const float* __restrict__ x,
                             short* __restrict__ oh, short* __restrict__ ol){
  int idx = blockIdx.x * 256 + threadIdx.x;
  if (idx >= M * D) return;
  float f = x[idx];
  unsigned short h = f2bf(f);
  oh[idx] = (short)h; ol[idx] = (short)f2bf(f - bf2f(h));
}

// ---------------- layernorm D=384: f32 in -> hi/lo bf16 out ----------------
__global__ __launch_bounds__(256)
void layernorm_bf(const float* __restrict__ x, const float* __restrict__ w,
                  const float* __restrict__ bb, short* __restrict__ oh,
                  short* __restrict__ ol){
  int wave = threadIdx.x >> 6, lane = threadIdx.x & 63;
  int row = blockIdx.x * 4 + wave;
  const float* xr = x + (size_t)row * D;
  float v[6], s = 0.f, sq = 0.f;
  #pragma unroll
  for (int i = 0; i < 6; i++){ v[i] = xr[lane + 64 * i]; s += v[i]; sq += v[i] * v[i]; }
  #pragma unroll
  for (int off = 32; off; off >>= 1){ s += __shfl_xor(s, off); sq += __shfl_xor(sq, off); }
  float mean = s * (1.f / D);
  float var  = sq * (1.f / D) - mean * mean;
  float inv  = 1.0f / sqrtf(var + 1e-5f);
  #pragma unroll
  for (int i = 0; i < 6; i++){
    int c = lane + 64 * i;
    float o = (v[i] - mean) * inv * w[c] + bb[c];
    unsigned short h = f2bf(o);
    oh[(size_t)row * D + c] = (short)h;
    ol[(size_t)row * D + c] = (short)f2bf(o - bf2f(h));
  }
}

// ---------------- final layernorm: f32 -> f32 ----------------
__global__ __launch_bounds__(256)
void layernorm_f32(const float* __restrict__ x, const float* __restrict__ w,
                   const float* __restrict__ bb, float* __restrict__ outf){
  int wave = threadIdx.x >> 6, lane = threadIdx.x & 63;
  int row = blockIdx.x * 4 + wave;
  const float* xr = x + (size_t)row * D;
  float v[6], s = 0.f, sq = 0.f;
  #pragma unroll
  for (int i = 0; i < 6; i++){ v[i] = xr[lane + 64 * i]; s += v[i]; sq += v[i] * v[i]; }
  #pragma unroll
  for (int off = 32; off; off >>= 1){ s += __shfl_xor(s, off); sq += __shfl_xor(sq, off); }
  float mean = s * (1.f / D);
  float var  = sq * (1.f / D) - mean * mean;
  float inv  = 1.0f / sqrtf(var + 1e-5f);
  #pragma unroll
  for (int i = 0; i < 6; i++){
    int c = lane + 64 * i;
    outf[(size_t)row * D + c] = (v[i] - mean) * inv * w[c] + bb[c];
  }
}

// ---------------- MFMA GEMM, row-major A (pre-split hi/lo) ----------------
// EPI: 0 = bias -> C[m*ncols+n]; 1 = +pos -> C; 2 = residual add in-place;
//      4 = in-proj split: n<E -> xmT[n*M+m] (f32, transposed); n>=E -> C2[(n-E)*M+m]=silu
template<int WSEL, int EPI>
__global__ __launch_bounds__(256)
void gemm_bf(const short* __restrict__ Ah, const short* __restrict__ Al, int lda, int K,
             size_t woff, const float* __restrict__ bias,
             float* __restrict__ C, float* __restrict__ C2,
             const float* __restrict__ pos, int ncols){
  constexpr int BKp = 40;
  __shared__ __align__(16) short sAh[64 * BKp], sAl[64 * BKp];
  __shared__ __align__(16) short sWh[64 * BKp], sWl[64 * BKp];
  const short* Wh = wsel_h<WSEL>() + woff;
  const short* Wl = wsel_l<WSEL>() + woff;
  const int t = threadIdx.x, wid = t >> 6, lane = t & 63;
  const int m0 = blockIdx.y * 64, n0 = blockIdx.x * 64;

  fx4 acc[4];
  #pragma unroll
  for (int a = 0; a < 4; a++)
    #pragma unroll
    for (int i = 0; i < 4; i++) acc[a][i] = 0.f;

  const int r = t >> 2, kp = (t & 3) << 3;
  const int row = lane & 15, kq = lane >> 4;

  for (int kt = 0; kt < K; kt += 32){
    *(bf16x8*)&sAh[r * BKp + kp] = *(const bf16x8*)(Ah + (size_t)(m0 + r) * lda + kt + kp);
    *(bf16x8*)&sAl[r * BKp + kp] = *(const bf16x8*)(Al + (size_t)(m0 + r) * lda + kt + kp);
    *(bf16x8*)&sWh[r * BKp + kp] = *(const bf16x8*)(Wh + (size_t)(n0 + r) * K + kt + kp);
    *(bf16x8*)&sWl[r * BKp + kp] = *(const bf16x8*)(Wl + (size_t)(n0 + r) * K + kt + kp);
    __syncthreads();
    bf16x8 bh = *(const bf16x8*)&sWh[(wid * 16 + row) * BKp + kq * 8];
    bf16x8 bl = *(const bf16x8*)&sWl[(wid * 16 + row) * BKp + kq * 8];
    #pragma unroll
    for (int tm = 0; tm < 4; tm++){
      bf16x8 ah = *(const bf16x8*)&sAh[(tm * 16 + row) * BKp + kq * 8];
      bf16x8 al = *(const bf16x8*)&sAl[(tm * 16 + row) * BKp + kq * 8];
      acc[tm] = __builtin_amdgcn_mfma_f32_16x16x32_bf16(ah, bh, acc[tm], 0, 0, 0);
      acc[tm] = __builtin_amdgcn_mfma_f32_16x16x32_bf16(ah, bl, acc[tm], 0, 0, 0);
      acc[tm] = __builtin_amdgcn_mfma_f32_16x16x32_bf16(al, bh, acc[tm], 0, 0, 0);
    }
    __syncthreads();
  }

  const int row4 = (lane >> 4) * 4, coln = lane & 15;
  #pragma unroll
  for (int tm = 0; tm < 4; tm++){
    int n = n0 + wid * 16 + coln;
    int mb = m0 + tm * 16 + row4;
    if constexpr (EPI == 4){
      float4 v4;
      float* vp = (float*)&v4;
      #pragma unroll
      for (int i = 0; i < 4; i++) vp[i] = acc[tm][i] + bias[n];
      if (n < E){
        *(float4*)&C[(size_t)n * M + mb] = v4;          // xmT transposed
      } else {
        #pragma unroll
        for (int i = 0; i < 4; i++){
          float sig = 1.f / (1.f + expf(-vp[i]));
          vp[i] = vp[i] * sig;
        }
        *(float4*)&C2[(size_t)(n - E) * M + mb] = v4;   // zst transposed
      }
    } else {
      #pragma unroll
      for (int i = 0; i < 4; i++){
        int m = mb + i;
        float v = acc[tm][i] + bias[n];
        if constexpr (EPI == 1) v += pos[(size_t)(m & (Np - 1)) * ncols + n];
        if constexpr (EPI == 2) v += C[(size_t)m * ncols + n];
        C[(size_t)m * ncols + n] = v;
      }
    }
  }
}

// ---------------- MFMA GEMM, TRANSPOSED A ([K][M] hi/lo shorts), EPI=residual add ----------------
__global__ __launch_bounds__(256)
void gemm_bf_at(const short* __restrict__ ATh, const short* __restrict__ ATl, int K,
                size_t woff, const float* __restrict__ bias,
                float* __restrict__ C, int ncols){
  constexpr int BKp = 40;
  __shared__ __align__(16) short sAh[64 * BKp], sAl[64 * BKp];
  __shared__ __align__(16) short sWh[64 * BKp], sWl[64 * BKp];
  const short* Wh = g_ow_h + woff;
  const short* Wl = g_ow_l + woff;
  const int t = threadIdx.x, wid = t >> 6, lane = t & 63;
  const int m0 = blockIdx.y * 64, n0 = blockIdx.x * 64;

  fx4 acc[4];
  #pragma unroll
  for (int a = 0; a < 4; a++)
    #pragma unroll
    for (int i = 0; i < 4; i++) acc[a][i] = 0.f;

  const int rw = t >> 2, kpw = (t & 3) << 3;        // W staging (row-major)
  const int kr2 = (t & 15) * 2, mc4 = (t >> 4) * 4; // A staging (transposed)
  const int row = lane & 15, kq = lane >> 4;

  for (int kt = 0; kt < K; kt += 32){
    { // A: rows kr2,kr2+1 of AT, 4 m each; pack pairs -> b32 LDS writes
      const uint2 h0 = *(const uint2*)(ATh + (size_t)(kt + kr2) * M + m0 + mc4);
      const uint2 h1 = *(const uint2*)(ATh + (size_t)(kt + kr2 + 1) * M + m0 + mc4);
      const uint2 l0 = *(const uint2*)(ATl + (size_t)(kt + kr2) * M + m0 + mc4);
      const uint2 l1 = *(const uint2*)(ATl + (size_t)(kt + kr2 + 1) * M + m0 + mc4);
      const unsigned int h0a[2] = {h0.x, h0.y}, h1a[2] = {h1.x, h1.y};
      const unsigned int l0a[2] = {l0.x, l0.y}, l1a[2] = {l1.x, l1.y};
      #pragma unroll
      for (int j = 0; j < 4; j++){
        unsigned int s0 = (h0a[j >> 1] >> ((j & 1) * 16)) & 0xFFFFu;
        unsigned int s1 = (h1a[j >> 1] >> ((j & 1) * 16)) & 0xFFFFu;
        *(unsigned int*)&sAh[(mc4 + j) * BKp + kr2] = s0 | (s1 << 16);
        unsigned int t0 = (l0a[j >> 1] >> ((j & 1) * 16)) & 0xFFFFu;
        unsigned int t1 = (l1a[j >> 1] >> ((j & 1) * 16)) & 0xFFFFu;
        *(unsigned int*)&sAl[(mc4 + j) * BKp + kr2] = t0 | (t1 << 16);
      }
    }
    *(bf16x8*)&sWh[rw * BKp + kpw] = *(const bf16x8*)(Wh + (size_t)(n0 + rw) * K + kt + kpw);
    *(bf16x8*)&sWl[rw * BKp + kpw] = *(const bf16x8*)(Wl + (size_t)(n0 + rw) * K + kt + kpw);
    __syncthreads();
    bf16x8 bh = *(const bf16x8*)&sWh[(wid * 16 + row) * BKp + kq * 8];
    bf16x8 bl = *(const bf16x8*)&sWl[(wid * 16 + row) * BKp + kq * 8];
    #pragma unroll
    for (int tm = 0; tm < 4; tm++){
      bf16x8 ah = *(const bf16x8*)&sAh[(tm * 16 + row) * BKp + kq * 8];
      bf16x8 al = *(const bf16x8*)&sAl[(tm * 16 + row) * BKp + kq * 8];
      acc[tm] = __builtin_amdgcn_mfma_f32_16x16x32_bf16(ah, bh, acc[tm], 0, 0, 0);
      acc[tm] = __builtin_amdgcn_mfma_f32_16x16x32_bf16(ah, bl, acc[tm], 0, 0, 0);
      acc[tm] = __builtin_amdgcn_mfma_f32_16x16x32_bf16(al, bh, acc[tm], 0, 0, 0);
    }
    __syncthreads();
  }

  const int row4 = (lane >> 4) * 4, coln = lane & 15;
  #pragma unroll
  for (int tm = 0; tm < 4; tm++)
    #pragma unroll
    for (int i = 0; i < 4; i++){
      int m = m0 + tm * 16 + row4 + i;
      int n = n0 + wid * 16 + coln;
      float v = acc[tm][i] + bias[n] + C[(size_t)m * ncols + n];
      C[(size_t)m * ncols + n] = v;
    }
}

// ---------------- xp GEMM (K-split, partial outputs): xBC4[p][M][32] ----------------
__global__ __launch_bounds__(256)
void gemm_xp(const float* __restrict__ xcT, const float* __restrict__ W,
             const float* __restrict__ bias, float* __restrict__ C4){
  __shared__ float As[16][64 + 1];
  __shared__ float Ws[16][32 + 1];
  int tid = threadIdx.x;
  int tx = tid & 15, ty = tid >> 4;
  int m0 = blockIdx.y * 64, kb = blockIdx.x * 192;
  float acc[4][2];
  #pragma unroll
  for (int i = 0; i < 4; i++){ acc[i][0] = 0.f; acc[i][1] = 0.f; }
  for (int kt = kb; kt < kb + 192; kt += 16){
    #pragma unroll
    for (int ps = 0; ps < 4; ps++){
      int rr = (tid >> 6) + 4 * ps, mc = tid & 63;
      As[rr][mc] = xcT[(size_t)(kt + rr) * M + m0 + mc];
    }
    if (tid < 128){
      int c = tid >> 2, kk = (tid & 3) << 2;
      const float* wp = W + (size_t)c * E + kt + kk;
      Ws[kk + 0][c] = wp[0]; Ws[kk + 1][c] = wp[1];
      Ws[kk + 2][c] = wp[2]; Ws[kk + 3][c] = wp[3];
    }
    __syncthreads();
    #pragma unroll
    for (int k = 0; k < 16; k++){
      float a[4], w[2];
      #pragma unroll
      for (int i = 0; i < 4; i++) a[i] = As[k][ty * 4 + i];
      w[0] = Ws[k][tx * 2]; w[1] = Ws[k][tx * 2 + 1];
      #pragma unroll
      for (int i = 0; i < 4; i++){ acc[i][0] += a[i] * w[0]; acc[i][1] += a[i] * w[1]; }
    }
    __syncthreads();
  }
  float* Cp = C4 + (size_t)blockIdx.x * M * 32;
  #pragma unroll
  for (int i = 0; i < 4; i++){
    int m = m0 + ty * 4 + i;
    #pragma unroll
    for (int j = 0; j < 2; j++){
      int n = tx * 2 + j;
      float v = acc[i][j];
      if (blockIdx.x == 0) v += bias[n];
      Cp[(size_t)m * 32 + n] = v;
    }
  }
}

// ---------------- dt GEMM: sums xBC4 partials, writes dt^T and fused xBC ----------------
__global__ __launch_bounds__(256)
void gemm_dt(const float* __restrict__ C4, const float* __restrict__ W,
             const float* __restrict__ bias, float* __restrict__ dtt,
             float* __restrict__ xBC){
  __shared__ float As[32][64 + 1];
  __shared__ float Ws[16][64 + 1];
  int tid = threadIdx.x;
  int tx = tid & 15, ty = tid >> 4;
  int m0 = blockIdx.y * 64, n0 = blockIdx.x * 64;
  { // stage A: sum 4 partials
    int mm = tid & 63, k8 = (tid >> 6) * 8;
    float s[8];
    #pragma unroll
    for (int j = 0; j < 8; j++) s[j] = 0.f;
    #pragma unroll
    for (int p = 0; p < 4; p++){
      const float* src = C4 + (size_t)p * M * 32 + (size_t)(m0 + mm) * 32 + k8;
      float4 a = *(const float4*)src, b = *(const float4*)(src + 4);
      s[0] += a.x; s[1] += a.y; s[2] += a.z; s[3] += a.w;
      s[4] += b.x; s[5] += b.y; s[6] += b.z; s[7] += b.w;
    }
    #pragma unroll
    for (int j = 0; j < 8; j++) As[k8 + j][mm] = s[j];
    if (blockIdx.x == 0){
      float* dst = xBC + (size_t)(m0 + mm) * 32 + k8;
      *(float4*)dst = make_float4(s[0], s[1], s[2], s[3]);
      *(float4*)(dst + 4) = make_float4(s[4], s[5], s[6], s[7]);
    }
  }
  { // stage W (K=16)
    int rr = tid >> 2, kk = (tid & 3) << 2;
    const float* wp = W + (size_t)(n0 + rr) * 16 + kk;
    Ws[kk + 0][rr] = wp[0]; Ws[kk + 1][rr] = wp[1];
    Ws[kk + 2][rr] = wp[2]; Ws[kk + 3][rr] = wp[3];
  }
  __syncthreads();
  float acc[4][4];
  #pragma unroll
  for (int i = 0; i < 4; i++)
    #pragma unroll
    for (int j = 0; j < 4; j++) acc[i][j] = 0.f;
  #pragma unroll
  for (int k = 0; k < 16; k++){
    float a[4], w[4];
    #pragma unroll
    for (int i = 0; i < 4; i++) a[i] = As[k][ty * 4 + i];
    #pragma unroll
    for (int j = 0; j < 4; j++) w[j] = Ws[k][tx * 4 + j];
    #pragma unroll
    for (int i = 0; i < 4; i++)
      #pragma unroll
      for (int j = 0; j < 4; j++) acc[i][j] += a[i] * w[j];
  }
  #pragma unroll
  for (int i = 0; i < 4; i++){
    int m = m0 + ty * 4 + i;
    #pragma unroll
    for (int j = 0; j < 4; j++){
      int n = n0 + tx * 4 + j;
      float v = acc[i][j] + bias[n];
      v = (v > 15.f) ? v : log1pf(expf(v));
      v = fminf(fmaxf(v, 1e-4f), 1.0f);
      dtt[(size_t)n * M + m] = v;
    }
  }
}

// ---------------- depthwise causal conv (K=4) + SiLU on transposed layout ----------------
__global__ __launch_bounds__(256)
void conv_silu_t(const float* __restrict__ xmT, const float* __restrict__ cw,
                 const float* __restrict__ cb, float* __restrict__ xcT){
  const int e = blockIdx.x, t = threadIdx.x;
  const float w0 = cw[e * 4], w1 = cw[e * 4 + 1], w2 = cw[e * 4 + 2], w3 = cw[e * 4 + 3];
  const float bias = cb[e];
  const float* src = xmT + (size_t)e * M;
  float* dst = xcT + (size_t)e * M;
  int mb = t * 8;
  #pragma unroll
  for (int j = 0; j < 8; j++){
    int m = mb + j, n = m & (Np - 1);
    float acc = bias + w3 * src[m];
    if (n >= 1) acc += w2 * src[m - 1];
    if (n >= 2) acc += w1 * src[m - 2];
    if (n >= 3) acc += w0 * src[m - 3];
    float sig = 1.f / (1.f + expf(-acc));
    dst[m] = acc * sig;
  }
}

// ---------------- chunked selective scan (DPP reduce, transposed IO) ----------------
__global__ __launch_bounds__(256)
void scan_kernel(const float* __restrict__ dtt, const float* __restrict__ xcT,
                 const float* __restrict__ zst, const float* __restrict__ xBC,
                 const float* __restrict__ Aptr, const float* __restrict__ Dp,
                 short* __restrict__ yh, short* __restrict__ yl){
  __shared__ float yloc[16 * 65];
  __shared__ float sdt[64 * 17], sxc[64 * 17];
  __shared__ float hloc[16][16], prodA[16][16], Hin[16][16];
  const int t = threadIdx.x, g = t >> 4, s = t & 15;
  const int r = blockIdx.x, b = r / E, e = r % E;
  const float a   = Aptr[e * S + s];
  const float dpe = Dp[e];
  const float* dtp = dtt + (size_t)e * M + b * Np;
  const float* xcp = xcT + (size_t)e * M + b * Np;
  const float* zsp = zst + (size_t)e * M + b * Np;

  // preload dt, xc rows into LDS (17-stride transposed: conflict-free R/W)
  #pragma unroll
  for (int q = t; q < 1024; q += 256){
    sdt[(q & 63) * 17 + (q >> 6)] = dtp[q];
    sxc[(q & 63) * 17 + (q >> 6)] = xcp[q];
  }
  __syncthreads();

  const int n0 = g * 64;
  const int mbase = b * Np + n0;

  float h = 0.f, P = 1.f;
  #pragma unroll 8
  for (int i = 0; i < 64; i++){
    int m = mbase + i;
    float dt  = sdt[i * 17 + g];
    float xcv = sxc[i * 17 + g];
    float xb  = xBC[m * 32 + s];
    float xcs = xBC[m * 32 + 16 + s];
    float dA = __expf(fmaxf(dt * a, -20.f));
    h = dA * h + xb * xcv;
    P *= dA;
    float p = row_sum16(h * xcs);
    if (s == 0) yloc[g * 65 + i] = p + dpe * xcv;
  }
  hloc[g][s] = h; prodA[g][s] = P;
  __syncthreads();
  if (t < 16){
    float H = 0.f;
    #pragma unroll
    for (int g2 = 0; g2 < 16; g2++){
      Hin[g2][t] = H;
      H = prodA[g2][t] * H + hloc[g2][t];
    }
  }
  __syncthreads();
  float Q = Hin[g][s];
  #pragma unroll 8
  for (int i = 0; i < 64; i++){
    int m = mbase + i;
    float dt  = sdt[i * 17 + g];
    float xcs = xBC[m * 32 + 16 + s];
    float dA = __expf(fmaxf(dt * a, -20.f));
    Q *= dA;
    float p = row_sum16(Q * xcs);
    if (s == 0) yloc[g * 65 + i] += p;
  }
  __syncthreads();
  { // coalesced hi/lo bf16 write, [e][m] layout
    int n4 = t * 4;
    float4 z4 = *(const float4*)&zsp[n4];
    const float* zp = (const float*)&z4;
    int gy = n4 >> 6, iy = n4 & 63;
    unsigned int hpack[2], lpack[2];
    #pragma unroll
    for (int half = 0; half < 2; half++){
      unsigned int hp = 0, lp = 0;
      #pragma unroll
      for (int j = 0; j < 2; j++){
        float val = yloc[gy * 65 + iy + half * 2 + j] * zp[half * 2 + j];
        unsigned short hh = f2bf(val);
        unsigned short ll = f2bf(val - bf2f(hh));
        hp |= ((unsigned int)hh) << (16 * j);
        lp |= ((unsigned int)ll) << (16 * j);
      }
      hpack[half] = hp; lpack[half] = lp;
    }
    size_t o = (size_t)e * M + b * Np + n4;
    *(uint2*)&yh[o] = make_uint2(hpack[0], hpack[1]);
    *(uint2*)&yl[o] = make_uint2(lpack[0], lpack[1]);
  }
}

extern "C" void kernel_launch(void* const* d_in, const int* in_sizes, int n_in,
                              void* d_out, int out_size, void* d_ws, size_t ws_size,
                              hipStream_t stream){
  const float* px      = (const float*)d_in[0];
  const float* patch_w = (const float*)d_in[1];
  const float* patch_b = (const float*)d_in[2];
  const float* pos     = (const float*)d_in[3];
  const float* norm_w  = (const float*)d_in[4];
  const float* norm_b  = (const float*)d_in[5];
  const float* in_w    = (const float*)d_in[6];
  const float* in_b    = (const float*)d_in[7];
  const float* conv_w  = (const float*)d_in[8];
  const float* conv_b  = (const float*)d_in[9];
  const float* xp_w    = (const float*)d_in[10];
  const float* xp_b    = (const float*)d_in[11];
  const float* dt_w    = (const float*)d_in[12];
  const float* dt_b    = (const float*)d_in[13];
  const float* Aab     = (const float*)d_in[14];
  const float* Dp      = (const float*)d_in[15];
  const float* out_w   = (const float*)d_in[16];
  const float* out_b   = (const float*)d_in[17];
  const float* fnorm_w = (const float*)d_in[18];
  const float* fnorm_b = (const float*)d_in[19];
  const float* scale_w = (const float*)d_in[20];
  const float* scale_b = (const float*)d_in[21];
  float* out = (float*)d_out;

  // workspace (30.25 MB)
  float* x   = (float*)d_ws;                  // M*D
  float* xmT = x + (size_t)M * D;             // E*M f32 (transposed x_main)
  float* zst = xmT + (size_t)M * E;           // E*M
  float* xcT = zst + (size_t)M * E;           // E*M
  float* xBC = xcT + (size_t)M * E;           // M*32
  float* dtt = xBC + (size_t)M * 32;          // E*M
  short* xnh = (short*)(dtt + (size_t)M * E); // M*D
  short* xnl = xnh + (size_t)M * D;           // M*D
  float* xBC4 = (float*)xnh;                  // 4*M*32 (alias)
  short* yh  = (short*)xmT;                   // E*M shorts (alias: dead x_main)
  short* yl  = yh + (size_t)M * E;
  short* pbh = yh, *pbl = yl;                 // patch buffer alias

  constexpr size_t TOTW = PW_N + IW_N + OW_N + SW_N;
  convw_kernel<<<(int)((TOTW + 255) / 256), 256, 0, stream>>>(patch_w, in_w, out_w, scale_w);

  patchify_kernel<<<(M * 768 + 255) / 256, 256, 0, stream>>>(px, pbh, pbl);
  gemm_bf<0, 1><<<dim3(D / 64, M / 64), 256, 0, stream>>>(
      pbh, pbl, 768, 768, 0, patch_b, x, nullptr, pos, D);

  for (int l = 0; l < L; l++){
    layernorm_bf<<<M / 4, 256, 0, stream>>>(x, norm_w + l * D, norm_b + l * D, xnh, xnl);
    gemm_bf<1, 4><<<dim3(TWO_E / 64, M / 64), 256, 0, stream>>>(
        xnh, xnl, D, D, (size_t)l * TWO_E * D, in_b + l * TWO_E, xmT, zst, nullptr, TWO_E);
    conv_silu_t<<<E, 256, 0, stream>>>(
        xmT, conv_w + (size_t)l * E * 4, conv_b + l * E, xcT);
    gemm_xp<<<dim3(4, M / 64), 256, 0, stream>>>(
        xcT, xp_w + (size_t)l * 32 * E, xp_b + l * 32, xBC4);
    gemm_dt<<<dim3(E / 64, M / 64), 256, 0, stream>>>(
        xBC4, dt_w + (size_t)l * E * S, dt_b + l * E, dtt, xBC);
    scan_kernel<<<Bz * E, 256, 0, stream>>>(
        dtt, xcT, zst, xBC, Aab + (size_t)l * E * S, Dp + l * E, yh, yl);
    gemm_bf_at<<<dim3(D / 64, M / 64), 256, 0, stream>>>(
        yh, yl, E, (size_t)l * D * E, out_b + l * D, x, D);
    if (l % 4 == 0 && l / 4 < 3){
      int j = l / 4;
      convx_kernel<<<(M * D + 255) / 256, 256, 0, stream>>>(x, xnh, xnl);
      gemm_bf<3, 0><<<dim3(D / 64, M / 64), 256, 0, stream>>>(
          xnh, xnl, D, D, (size_t)j * D * D, scale_b + j * D,
          out + (size_t)(1 + j) * M * D, nullptr, nullptr, D);
    }
  }
  layernorm_f32<<<M / 4, 256, 0, stream>>>(x, fnorm_w, fnorm_b, out);
}